// Round 10
// baseline (253.442 us; speedup 1.0000x reference)
//
#include <hip/hip_runtime.h>

typedef __bf16 v8bf __attribute__((ext_vector_type(8)));
typedef float f32x4 __attribute__((ext_vector_type(4)));

#define DEVI static __device__ __forceinline__

DEVI v8bf load8(const __bf16* p) { return *reinterpret_cast<const v8bf*>(p); }

DEVI f32x4 mfma16(v8bf a, v8bf b, f32x4 c) {
  return __builtin_amdgcn_mfma_f32_16x16x32_bf16(a, b, c, 0, 0, 0);
}

// async global -> LDS, 16 bytes per lane. LDS dest: wave-uniform base + lane*16.
DEVI void gld16(const __bf16* g, __bf16* l) {
  __builtin_amdgcn_global_load_lds(
      (const __attribute__((address_space(1))) unsigned int*)(const void*)g,
      (__attribute__((address_space(3))) unsigned int*)(void*)l, 16, 0, 0);
}

#define SCALE_Q 0.08838834764831845f  // 128^-0.5

// ------------------------------------------------------------------
// Fused prologue: casts, conv-weight repack, zpad zero. One launch.
// ------------------------------------------------------------------
__global__ void k_prep(const float* __restrict__ wqk, const float* __restrict__ wv,
                       const float* __restrict__ relh, const float* __restrict__ relw,
                       const float* __restrict__ wfc, __bf16* __restrict__ wqkb,
                       __bf16* __restrict__ wvb, __bf16* __restrict__ rhb,
                       __bf16* __restrict__ rwb, __bf16* __restrict__ Wt,
                       float* __restrict__ zpad4) {
  const int bid = blockIdx.x, tid = threadIdx.x;
  if (bid < 2048) {
    int i = bid * 256 + tid;
    wqkb[i] = (__bf16)wqk[i];
  } else if (bid < 3072) {
    int i = (bid - 2048) * 256 + tid;
    wvb[i] = (__bf16)wv[i];
  } else if (bid < 3104) {
    int i = (bid - 3072) * 256 + tid;
    if (i < 8064) rhb[i] = (__bf16)relh[i];
  } else if (bid < 3136) {
    int i = (bid - 3104) * 256 + tid;
    if (i < 8064) rwb[i] = (__bf16)relw[i];
  } else if (bid < 4160) {
    int i = (bid - 3136) * 256 + tid;    // (o,c) pair
    const float* src = wfc + (size_t)i * 9;
#pragma unroll
    for (int tap = 0; tap < 9; ++tap)
      Wt[(size_t)tap * 262144 + i] = (__bf16)src[tap];
  } else {
    int i = (bid - 4160) * 256 + tid;
    f32x4 z = {0.f, 0.f, 0.f, 0.f};
    reinterpret_cast<f32x4*>(zpad4)[i] = z;
  }
}

// ------------------------------------------------------------------
// BN1 + ReLU on fp32 x, transpose (b,c,s) -> (b,s,c), bf16 out
// ------------------------------------------------------------------
__global__ void k_bn1(const float* __restrict__ x, const float* __restrict__ g,
                      const float* __restrict__ bb, const float* __restrict__ m,
                      const float* __restrict__ v, __bf16* __restrict__ y) {
  __shared__ float tile[32][33];
  const int b = blockIdx.z, c0 = blockIdx.y * 32, s0 = blockIdx.x * 32;
  const int tx = threadIdx.x, ty = threadIdx.y;   // 32 x 8
#pragma unroll
  for (int r = 0; r < 4; ++r) {
    int c = c0 + ty + r * 8;
    float inv = g[c] * rsqrtf(v[c] + 1e-5f);
    float beta = bb[c] - m[c] * inv;
    float val = x[((size_t)b * 512 + c) * 1024 + s0 + tx] * inv + beta;
    tile[ty + r * 8][tx] = fmaxf(val, 0.0f);
  }
  __syncthreads();
#pragma unroll
  for (int r = 0; r < 4; ++r) {
    int s = s0 + ty + r * 8;
    y[((size_t)b * 1024 + s) * 512 + c0 + tx] = (__bf16)tile[tx][ty + r * 8];
  }
}

// ------------------------------------------------------------------
// BN2 + ReLU on fp32 x2 (FINAL, attn already added x), transpose
// (b,c,s) -> padded (b,34,34,c) bf16.  (original cheap version)
// ------------------------------------------------------------------
__global__ void k_bn2(const float* __restrict__ x2, const float* __restrict__ g,
                      const float* __restrict__ bb, const float* __restrict__ m,
                      const float* __restrict__ v, __bf16* __restrict__ zp) {
  __shared__ float tile[32][33];
  const int b = blockIdx.z, c0 = blockIdx.y * 32, s0 = blockIdx.x * 32;
  const int tx = threadIdx.x, ty = threadIdx.y;
#pragma unroll
  for (int r = 0; r < 4; ++r) {
    int c = c0 + ty + r * 8;
    float inv = g[c] * rsqrtf(v[c] + 1e-5f);
    float beta = bb[c] - m[c] * inv;
    float val = x2[((size_t)b * 512 + c) * 1024 + s0 + tx] * inv + beta;
    tile[ty + r * 8][tx] = fmaxf(val, 0.0f);
  }
  __syncthreads();
#pragma unroll
  for (int r = 0; r < 4; ++r) {
    int s = s0 + ty + r * 8;
    int hh = s >> 5, ww = s & 31;
    zp[(((size_t)b * 34 + hh + 1) * 34 + ww + 1) * 512 + c0 + tx] =
        (__bf16)tile[tx][ty + r * 8];
  }
}

// ------------------------------------------------------------------
// QKV projection, prefetch double-buffered (from r8, ~neutral).
// ------------------------------------------------------------------
__global__ __launch_bounds__(256) void k_proj(
    const __bf16* __restrict__ wall, const __bf16* __restrict__ y,
    __bf16* __restrict__ qout, __bf16* __restrict__ kout,
    __bf16* __restrict__ vout) {
  __shared__ __bf16 As[2][128 * 32];   // 16 KB
  __shared__ __bf16 Bs[2][128 * 32];   // 16 KB
  const int t = threadIdx.x;
  const int wave = t >> 6, lane = t & 63;
  const int l15 = lane & 15, quad = lane >> 4;
  const int mbase = blockIdx.x * 128;   // o in [0,1536)
  const int nbase = blockIdx.y * 128;   // flat (b,s)
  const int mh = (wave >> 1) * 64, nh = (wave & 1) * 64;
  const bool isv = mbase >= 1024;

  const int row0 = t >> 2, part8 = (t & 3) * 8;
  const __bf16* gA0 = wall + (size_t)(mbase + row0) * 512 + part8;
  const __bf16* gA1 = gA0 + (size_t)64 * 512;
  const __bf16* gB0 = y + (size_t)(nbase + row0) * 512 + part8;
  const __bf16* gB1 = gB0 + (size_t)64 * 512;
  const int wofs = wave * 512;

  const f32x4 fz = {0.f, 0.f, 0.f, 0.f};
  f32x4 acc[4][4];
#pragma unroll
  for (int i = 0; i < 4; ++i)
#pragma unroll
    for (int j = 0; j < 4; ++j) acc[i][j] = fz;

  // prologue: stage K-tile 0
  gld16(gA0, &As[0][wofs]);
  gld16(gA1, &As[0][2048 + wofs]);
  gld16(gB0, &Bs[0][wofs]);
  gld16(gB1, &Bs[0][2048 + wofs]);
  __syncthreads();

#pragma unroll 1
  for (int r = 0; r < 16; ++r) {
    const int cur = r & 1;
    if (r < 15) {
      const int kn = (r + 1) * 32;
      gld16(gA0 + kn, &As[cur ^ 1][wofs]);
      gld16(gA1 + kn, &As[cur ^ 1][2048 + wofs]);
      gld16(gB0 + kn, &Bs[cur ^ 1][wofs]);
      gld16(gB1 + kn, &Bs[cur ^ 1][2048 + wofs]);
    }
    v8bf a[4], bfr[4];
#pragma unroll
    for (int i = 0; i < 4; ++i)
      a[i] = load8(&As[cur][(mh + i * 16 + l15) * 32 + quad * 8]);
#pragma unroll
    for (int j = 0; j < 4; ++j)
      bfr[j] = load8(&Bs[cur][(nh + j * 16 + l15) * 32 + quad * 8]);
    if (isv) {
#pragma unroll
      for (int i = 0; i < 4; ++i)
#pragma unroll
        for (int j = 0; j < 4; ++j) acc[i][j] = mfma16(a[i], bfr[j], acc[i][j]);
    } else {
#pragma unroll
      for (int i = 0; i < 4; ++i)
#pragma unroll
        for (int j = 0; j < 4; ++j) acc[i][j] = mfma16(bfr[j], a[i], acc[i][j]);
    }
    __syncthreads();
  }

  if (isv) {
#pragma unroll
    for (int i = 0; i < 4; ++i)
#pragma unroll
      for (int j = 0; j < 4; ++j)
#pragma unroll
        for (int r = 0; r < 4; ++r) {
          int o = mbase + mh + i * 16 + quad * 4 + r;
          int nflat = nbase + nh + j * 16 + l15;
          int b = nflat >> 10, s = nflat & 1023;
          int oe = o - 1024; int n = oe >> 7, d = oe & 127;
          vout[(((size_t)b * 4 + n) * 128 + d) * 1024 + s] = (__bf16)acc[i][j][r];
        }
  } else {
    const bool isq = mbase < 512;
#pragma unroll
    for (int i = 0; i < 4; ++i)
#pragma unroll
      for (int j = 0; j < 4; ++j)
#pragma unroll
        for (int r = 0; r < 4; ++r) {
          int o = mbase + mh + i * 16 + l15;
          int nflat = nbase + nh + j * 16 + quad * 4 + r;
          int b = nflat >> 10, s = nflat & 1023;
          float val = acc[i][j][r];
          if (isq) {
            int n = o >> 7, d = o & 127;
            qout[(((size_t)b * 4 + n) * 1024 + s) * 128 + d] = (__bf16)(val * SCALE_Q);
          } else {
            int oe = o - 512; int n = oe >> 7, d = oe & 127;
            kout[(((size_t)b * 4 + n) * 1024 + s) * 128 + d] = (__bf16)val;
          }
        }
  }
}

// ------------------------------------------------------------------
// Flash attention v13: FUSED split-K. 512-thread block = 2 wave-groups;
// wg0 = keys 0..511, wg1 = keys 512..1023, each running the verified
// v12 ladder (same per-thread vmcnt ledger, group-local staging, per-
// group Ks/Vs). Grid 256 = exactly 1 block/CU (8 waves/CU, same total
// waves as the 512-block split version). RW/RH tables computed once
// (wg0), shared. P = 16-row per-wave bands (write band h, read pf[h],
// overwrite -- within-wave in-order LDS). Epilogue: partner waves
// (w, w+4) exchange O/l via LDS overlay on dead Ks/Vs, write FINAL
// x2 = (o0+o1)/(l0+l1) + x. Kills o0/o1/lpart globals + bn2c traffic.
// ------------------------------------------------------------------
__global__ __launch_bounds__(512, 2) void k_attn(
    const __bf16* __restrict__ q, const __bf16* __restrict__ kmat,
    const __bf16* __restrict__ vt, const __bf16* __restrict__ relh,
    const __bf16* __restrict__ relw, const float* __restrict__ x,
    float* __restrict__ x2) {
  // manual LDS layout (58880 B), epilogue overlays xbuf/lb on [0,34304)
  __shared__ __attribute__((aligned(16))) char smem[58880];
  __bf16* Ks = (__bf16*)smem;                    // 2 wg x 4096 elems (16 KB)
  __bf16* Vs = (__bf16*)(smem + 16384);          // 2 wg x 4096 elems (16 KB)
  __bf16* P  = (__bf16*)(smem + 32768);          // 8 waves x 16x36 (9216 B)
  auto RWs = (__bf16(*)[33])(smem + 41984);      // [128][33] (8448 B)
  auto RHs = (__bf16(*)[33])(smem + 50432);      // [128][33] (8448 B)

  const int Lb = blockIdx.x;             // 0..255
  const int xcd = Lb & 7, local = Lb >> 3;   // local 0..31
  const int bn = xcd * 4 + (local & 3);
  const int qblk = local >> 2;           // 0..7 : 128 q-rows each
  const int s0 = qblk * 128;

  const int t = threadIdx.x;
  const int wave = t >> 6, lane = t & 63;
  const int wg = wave >> 2, w4 = wave & 3;
  const int tl = t & 255;                // group-local thread id
  const int l15 = lane & 15, quad = lane >> 4;
  const size_t hoff = ((size_t)bn) << 17;
  const int s0w = s0 + w4 * 32;          // wave owns rows s0w..s0w+31
  const int h0w = s0w >> 5;
  const int j00 = wg * 512;              // key-range base for this group

  // staging source pointers (group-local; identical mapping to v12)
  const __bf16* kgA =
      kmat + hoff + (size_t)((tl >> 2) & 31) * 128 + (tl >> 7) * 32 + (tl & 3) * 8;
  const __bf16* vgA = vt + hoff + (size_t)(tl >> 2) * 1024 + (tl & 3) * 8;
  __bf16* kbase = Ks + wg * 4096;
  __bf16* vbase = Vs + wg * 4096;
  __bf16* kswA = kbase + w4 * 512;       // wave-uniform dest base
  __bf16* vswA = vbase + w4 * 512;

  // issue first K/V tile -- latency hides under the bias prologue
#pragma unroll
  for (int c = 0; c < 2; ++c)
    gld16(kgA + (size_t)j00 * 128 + c * 64, kswA + c * 2048);
#pragma unroll
  for (int dh = 0; dh < 2; ++dh)
    gld16(vgA + (size_t)dh * 64 * 1024 + j00, vswA + dh * 2048);

  v8bf aq[2][4];
#pragma unroll
  for (int h = 0; h < 2; ++h) {
    const __bf16* qp = q + hoff + (size_t)(s0w + h * 16 + l15) * 128;
#pragma unroll
    for (int kk = 0; kk < 4; ++kk) aq[h][kk] = load8(qp + kk * 32 + quad * 8);
  }

  // bias tables: computed ONCE by wg0 (identical for both halves)
  if (wg == 0) {
#pragma unroll
    for (int h = 0; h < 2; ++h) {
#pragma unroll
      for (int nt = 0; nt < 4; ++nt) {   // RWs via shift-write
        int rr = nt * 16 + l15;
        const __bf16* bp = relw + (size_t)rr * 128;
        f32x4 acc = {0.f, 0.f, 0.f, 0.f};
#pragma unroll
        for (int kk = 0; kk < 4; ++kk)
          acc = mfma16(aq[h][kk], load8(bp + kk * 32 + quad * 8), acc);
#pragma unroll
        for (int r = 0; r < 4; ++r) {
          int row15 = quad * 4 + r;
          int wj = rr + h * 16 + row15 - 31;
          if (wj >= 0 && wj < 32)
            RWs[w4 * 32 + h * 16 + row15][wj] = (__bf16)acc[r];
        }
      }
#pragma unroll
      for (int nt = 0; nt < 2; ++nt) {   // RHs direct
        int hj = nt * 16 + l15;
        const __bf16* bp = relh + (size_t)(hj - h0w + 31) * 128;
        f32x4 acc = {0.f, 0.f, 0.f, 0.f};
#pragma unroll
        for (int kk = 0; kk < 4; ++kk)
          acc = mfma16(aq[h][kk], load8(bp + kk * 32 + quad * 8), acc);
#pragma unroll
        for (int r = 0; r < 4; ++r)
          RHs[w4 * 32 + h * 16 + quad * 4 + r][hj] = (__bf16)acc[r];
      }
    }
  }

  __syncthreads();   // tables visible to wg1; first K/V tiles landed

  // hoist rel-W bias (j-periodic mod 32) -- after barrier (cross-wave now)
  float rwreg[2][4][2];
#pragma unroll
  for (int h = 0; h < 2; ++h)
#pragma unroll
    for (int r = 0; r < 4; ++r) {
      const int gi = w4 * 32 + h * 16 + quad * 4 + r;
      rwreg[h][r][0] = (float)RWs[gi][l15];
      rwreg[h][r][1] = (float)RWs[gi][l15 + 16];
    }

  const f32x4 fz = {0.f, 0.f, 0.f, 0.f};
  float lsum[2][4];
#pragma unroll
  for (int h = 0; h < 2; ++h)
#pragma unroll
    for (int r = 0; r < 4; ++r) lsum[h][r] = 0.f;
  f32x4 oacc[2][8];
#pragma unroll
  for (int h = 0; h < 2; ++h)
#pragma unroll
    for (int dt = 0; dt < 8; ++dt) oacc[h][dt] = fz;
  __bf16* Pw16 = P + wave * 16 * 36;     // 16-row band, reused per h

#pragma unroll 1
  for (int iter = 0; iter < 16; ++iter) {
    // top: K_t ready-gate (outstanding: K_t oldest 2, V_t newest 2)
    asm volatile("s_waitcnt vmcnt(2)" ::: "memory");
    __builtin_amdgcn_s_barrier();
    __builtin_amdgcn_sched_barrier(0);

    // K fragments -> regs once, reused by both q-row tiles (h=0,1)
    v8bf kf[8];
#pragma unroll
    for (int nj = 0; nj < 2; ++nj)
#pragma unroll
      for (int kk = 0; kk < 4; ++kk)
        kf[nj * 4 + kk] =
            load8(&kbase[kk * 1024 + (nj * 16 + l15) * 32 + quad * 8]);

    // QK^T (16 MFMA covering 32q x 32j)
    f32x4 sacc[2][2];
    __builtin_amdgcn_s_setprio(1);
#pragma unroll
    for (int h = 0; h < 2; ++h)
#pragma unroll
      for (int nj = 0; nj < 2; ++nj) {
        f32x4 a = fz;
#pragma unroll
        for (int kk = 0; kk < 4; ++kk)
          a = mfma16(aq[h][kk], kf[nj * 4 + kk], a);
        sacc[h][nj] = a;
      }
    __builtin_amdgcn_s_setprio(0);

    // bias + exp(c=0) + partial l; P band written/read per h (in-wave order)
    const int hjb = wg * 16 + iter;
    v8bf pf[2];
#pragma unroll
    for (int h = 0; h < 2; ++h) {
#pragma unroll
      for (int r = 0; r < 4; ++r) {
        const int row15 = quad * 4 + r;
        const float rh0 = (float)RHs[w4 * 32 + h * 16 + row15][hjb];
#pragma unroll
        for (int nj = 0; nj < 2; ++nj) {
          float val = sacc[h][nj][r] + rwreg[h][r][nj] + rh0;
          float p = __expf(fminf(val, 60.0f));
          lsum[h][r] += p;
          Pw16[row15 * 36 + nj * 16 + l15] = (__bf16)p;
        }
      }
      pf[h] = *reinterpret_cast<const v8bf*>(&Pw16[l15 * 36 + quad * 8]);
    }

    // mid: V_t ready-gate; all waves past QK^T -> Ks overwrite safe
    asm volatile("s_waitcnt vmcnt(0)" ::: "memory");
    __builtin_amdgcn_s_barrier();
    __builtin_amdgcn_sched_barrier(0);

    // issue K[t+1] (covered by PV phase below)
    if (iter < 15) {
      const int jn = j00 + (iter + 1) * 32;
#pragma unroll
      for (int c = 0; c < 2; ++c)
        gld16(kgA + (size_t)jn * 128 + c * 64, kswA + c * 2048);
    }

    // PV as O^T = V * P^T (16 MFMA): V-frag read once, used by both h
    __builtin_amdgcn_s_setprio(1);
#pragma unroll
    for (int dt = 0; dt < 8; ++dt) {
      v8bf vf = load8(&vbase[(dt * 16 + l15) * 32 + quad * 8]);
#pragma unroll
      for (int h = 0; h < 2; ++h)
        oacc[h][dt] = mfma16(vf, pf[h], oacc[h][dt]);
    }
    __builtin_amdgcn_s_setprio(0);

    if (iter < 15) {
      // bottom: all waves' Vs reads retired -> V overwrite safe
      asm volatile("s_waitcnt lgkmcnt(0)" ::: "memory");
      __builtin_amdgcn_s_barrier();
      __builtin_amdgcn_sched_barrier(0);
      const int jn = j00 + (iter + 1) * 32;
#pragma unroll
      for (int dh = 0; dh < 2; ++dh)
        gld16(vgA + (size_t)dh * 64 * 1024 + jn, vswA + dh * 2048);
    }
  }

  // partial l: reduce across the 16-lane groups (j dimension)
#pragma unroll
  for (int h = 0; h < 2; ++h)
#pragma unroll
    for (int r = 0; r < 4; ++r) {
#pragma unroll
      for (int msk = 8; msk >= 1; msk >>= 1)
        lsum[h][r] += __shfl_xor(lsum[h][r], msk);
    }

  // ------- fused combine: pairs (w, w+4) exchange via LDS overlay -------
  float* xbuf = (float*)smem;                    // 64 x 132 f32 (33792 B)
  float* lb0 = (float*)(smem + 33792);           // 64 f32 (wg0 partial l)
  float* lb1 = lb0 + 64;                         // 64 f32 (wg1 partial l)

#pragma unroll 1
  for (int rnd = 0; rnd < 2; ++rnd) {
    __syncthreads();   // rnd0: loop LDS dead; rnd1: prev readers done
    if ((w4 >> 1) == rnd) {
      const int bA = w4 & 1;
      if (wg == 1) {
#pragma unroll
        for (int h = 0; h < 2; ++h) {
#pragma unroll
          for (int dt = 0; dt < 8; ++dt)
#pragma unroll
            for (int r = 0; r < 4; ++r)
              xbuf[(bA * 32 + h * 16 + l15) * 132 + dt * 16 + quad * 4 + r] =
                  oacc[h][dt][r];
          if (l15 == 0)
#pragma unroll
            for (int r = 0; r < 4; ++r)
              lb1[bA * 32 + h * 16 + quad * 4 + r] = lsum[h][r];
        }
      } else {
        if (l15 == 0)
#pragma unroll
          for (int h = 0; h < 2; ++h)
#pragma unroll
            for (int r = 0; r < 4; ++r)
              lb0[bA * 32 + h * 16 + quad * 4 + r] = lsum[h][r];
      }
    }
    __syncthreads();
    if (wg == 0 && (w4 >> 1) == rnd) {
      const int bA = w4 & 1;
#pragma unroll
      for (int h = 0; h < 2; ++h) {
        const int ri = bA * 32 + h * 16 + l15;
        const float linv = 1.0f / (lb0[ri] + lb1[ri]);
        const int s = s0w + h * 16 + l15;
#pragma unroll
        for (int dt = 0; dt < 8; ++dt)
#pragma unroll
          for (int r = 0; r < 4; ++r) {
            int d = dt * 16 + quad * 4 + r;
            size_t gi = ((size_t)bn * 128 + d) * 1024 + s;
            x2[gi] = (oacc[h][dt][r] + xbuf[ri * 132 + d]) * linv + x[gi];
          }
      }
    }
  }
}

// ------------------------------------------------------------------
// 3x3 conv (r9 verified): BK=128 two-barrier + XCD chunked swizzle.
// ------------------------------------------------------------------
__global__ __launch_bounds__(256, 2) void k_conv(
    const __bf16* __restrict__ Wt, const __bf16* __restrict__ zp,
    float* __restrict__ part) {
  __shared__ __bf16 As[4 * 128 * 32];   // 32 KB
  __shared__ __bf16 Bs[4 * 128 * 32];   // 32 KB
  const int t = threadIdx.x;
  const int wave = t >> 6, lane = t & 63;
  const int l15 = lane & 15, quad = lane >> 4;

  const int Lb = blockIdx.x;            // 0..511
  const int logical = (Lb & 7) * 64 + (Lb >> 3);   // XCD-chunked (bijective)
  const int combo = logical & 7;
  const int ot = combo >> 1, sp = combo & 1;
  const int nt = logical >> 3;          // 8 contiguous nt per XCD = 1 batch
  const int mbase = ot * 128;
  const int nbase = nt * 128;
  const int cs = sp * 256;
  const int mh = (wave >> 1) * 64, nh = (wave & 1) * 64;

  const int row0 = t >> 2;
  const int part8 = (t & 3) * 8;
  const __bf16* gA0 = Wt + (size_t)(mbase + row0) * 512 + cs + part8;
  const __bf16* gA1 = gA0 + (size_t)64 * 512;
  const int n0 = nbase + row0;
  const int b0 = n0 >> 10, spn = n0 & 1023;
  const __bf16* gB0 =
      zp + ((size_t)(b0 * 34 + (spn >> 5) + 1) * 34 + (spn & 31) + 1) * 512 + cs + part8;
  const __bf16* gB1 = gB0 + (size_t)2 * 34 * 512;
  const int wofs = wave * 512;

  const f32x4 fz = {0.f, 0.f, 0.f, 0.f};
  f32x4 acc[4][4];
#pragma unroll
  for (int i = 0; i < 4; ++i)
#pragma unroll
    for (int j = 0; j < 4; ++j) acc[i][j] = fz;

#pragma unroll 1
  for (int tap = 0; tap < 9; ++tap) {
    const int dh = tap / 3 - 1, dw = tap % 3 - 1;
    const size_t aoff = (size_t)tap * 512 * 512;
    const int boff = (dh * 34 + dw) * 512;
#pragma unroll 1
    for (int k0 = 0; k0 < 256; k0 += 128) {
      __syncthreads();
#pragma unroll
      for (int c = 0; c < 4; ++c) {
        const int kq = k0 + c * 32;
        gld16(gA0 + aoff + kq, As + c * 4096 + wofs);
        gld16(gA1 + aoff + kq, As + c * 4096 + 2048 + wofs);
        gld16(gB0 + boff + kq, Bs + c * 4096 + wofs);
        gld16(gB1 + boff + kq, Bs + c * 4096 + 2048 + wofs);
      }
      __syncthreads();
#pragma unroll
      for (int c = 0; c < 4; ++c) {
        v8bf a[4], bfr[4];
#pragma unroll
        for (int i = 0; i < 4; ++i)
          a[i] = load8(&As[c * 4096 + (mh + i * 16 + l15) * 32 + quad * 8]);
#pragma unroll
        for (int j = 0; j < 4; ++j)
          bfr[j] = load8(&Bs[c * 4096 + (nh + j * 16 + l15) * 32 + quad * 8]);
#pragma unroll
        for (int i = 0; i < 4; ++i)
#pragma unroll
          for (int j = 0; j < 4; ++j) acc[i][j] = mfma16(a[i], bfr[j], acc[i][j]);
      }
    }
  }

  float* pout = part + (size_t)sp * 8 * 512 * 1024;
#pragma unroll
  for (int i = 0; i < 4; ++i)
#pragma unroll
    for (int j = 0; j < 4; ++j)
#pragma unroll
      for (int r = 0; r < 4; ++r) {
        int o = mbase + mh + i * 16 + quad * 4 + r;
        int nn = nbase + nh + j * 16 + l15;
        int bb2 = nn >> 10, s = nn & 1023;
        pout[((size_t)bb2 * 512 + o) * 1024 + s] = acc[i][j][r];
      }
}

// ------------------------------------------------------------------
// out = part0 + part1 + bias + x2   (f32x4 vectorized)
// ------------------------------------------------------------------
__global__ void k_sum(const float* __restrict__ part, const float* __restrict__ bias,
                      const float* __restrict__ x2, float* __restrict__ out) {
  int i = blockIdx.x * 256 + threadIdx.x;
  int o = (i >> 8) & 511;
  f32x4 p0 = reinterpret_cast<const f32x4*>(part)[i];
  f32x4 p1 = reinterpret_cast<const f32x4*>(part + (size_t)8 * 512 * 1024)[i];
  f32x4 xr = reinterpret_cast<const f32x4*>(x2)[i];
  float bo = bias[o];
  f32x4 r;
#pragma unroll
  for (int c = 0; c < 4; ++c) r[c] = p0[c] + p1[c] + bo + xr[c];
  reinterpret_cast<f32x4*>(out)[i] = r;
}

// ------------------------------------------------------------------
extern "C" void kernel_launch(void* const* d_in, const int* in_sizes, int n_in,
                              void* d_out, int out_size, void* d_ws, size_t ws_size,
                              hipStream_t stream) {
  const float* x    = (const float*)d_in[0];
  const float* wqk  = (const float*)d_in[1];
  const float* wv   = (const float*)d_in[2];
  const float* relh = (const float*)d_in[3];
  const float* relw = (const float*)d_in[4];
  const float* g1   = (const float*)d_in[5];
  const float* b1   = (const float*)d_in[6];
  const float* m1   = (const float*)d_in[7];
  const float* v1   = (const float*)d_in[8];
  const float* g2   = (const float*)d_in[9];
  const float* b2   = (const float*)d_in[10];
  const float* m2   = (const float*)d_in[11];
  const float* v2   = (const float*)d_in[12];
  const float* wfc  = (const float*)d_in[13];
  const float* bfc  = (const float*)d_in[14];
  float* out = (float*)d_out;

  char* p = (char*)d_ws;
  __bf16* y    = (__bf16*)p; p += (size_t)8 * 1024 * 512 * 2;       // (b,s,c)
  __bf16* qb   = (__bf16*)p; p += (size_t)8 * 4 * 1024 * 128 * 2;   // (b,n,s,d)
  __bf16* kb   = (__bf16*)p; p += (size_t)8 * 4 * 1024 * 128 * 2;   // (b,n,s,d)
  __bf16* vb   = (__bf16*)p; p += (size_t)8 * 4 * 1024 * 128 * 2;   // (b,n,d,s)
  __bf16* Wt   = (__bf16*)p; p += (size_t)9 * 512 * 512 * 2;        // (tap,o,c)
  __bf16* wqkb = (__bf16*)p; p += (size_t)1024 * 512 * 2;           // wall rows 0..1023
  __bf16* wvb  = (__bf16*)p; p += (size_t)512 * 512 * 2;            // wall rows 1024..1535
  __bf16* rhb  = (__bf16*)p; p += 32768;
  __bf16* rwb  = (__bf16*)p; p += 32768;
  float*  x2   = (float*)p;  p += (size_t)8 * 512 * 1024 * 4;       // FINAL x2 (b,c,s) fp32
  __bf16* zpad = (__bf16*)p; p += (size_t)8 * 34 * 34 * 512 * 2;    // padded z
  // fp32 conv partials (2 x 16.78 MB) alias y+qb+kb+vb (dead after k_attn)
  float* part = (float*)d_ws;

  k_prep<<<dim3(6472), dim3(256), 0, stream>>>(wqk, wv, relh, relw, wfc,
                                               wqkb, wvb, rhb, rwb, Wt, (float*)zpad);
  k_bn1<<<dim3(32, 16, 8), dim3(32, 8), 0, stream>>>(x, g1, b1, m1, v1, y);
  k_proj<<<dim3(12, 64), dim3(256), 0, stream>>>(wqkb, y, qb, kb, vb);
  k_attn<<<dim3(256), dim3(512), 0, stream>>>(qb, kb, vb, rhb, rwb, x, x2);
  k_bn2<<<dim3(32, 16, 8), dim3(32, 8), 0, stream>>>(x2, g2, b2, m2, v2, zpad);
  k_conv<<<dim3(512), dim3(256), 0, stream>>>(Wt, zpad, part);
  k_sum<<<dim3(4096), dim3(256), 0, stream>>>(part, bfc, x2, out);
}

// Round 11
// 242.786 us; speedup vs baseline: 1.0439x; 1.0439x over previous
//
#include <hip/hip_runtime.h>

typedef __bf16 v8bf __attribute__((ext_vector_type(8)));
typedef float f32x4 __attribute__((ext_vector_type(4)));

#define DEVI static __device__ __forceinline__

DEVI v8bf load8(const __bf16* p) { return *reinterpret_cast<const v8bf*>(p); }

DEVI f32x4 mfma16(v8bf a, v8bf b, f32x4 c) {
  return __builtin_amdgcn_mfma_f32_16x16x32_bf16(a, b, c, 0, 0, 0);
}

// async global -> LDS, 16 bytes per lane. LDS dest: wave-uniform base + lane*16.
DEVI void gld16(const __bf16* g, __bf16* l) {
  __builtin_amdgcn_global_load_lds(
      (const __attribute__((address_space(1))) unsigned int*)(const void*)g,
      (__attribute__((address_space(3))) unsigned int*)(void*)l, 16, 0, 0);
}

#define SCALE_Q 0.08838834764831845f  // 128^-0.5

// ------------------------------------------------------------------
// Fused prologue: casts, conv-weight repack, zpad zero. One launch.
// ------------------------------------------------------------------
__global__ void k_prep(const float* __restrict__ wqk, const float* __restrict__ wv,
                       const float* __restrict__ relh, const float* __restrict__ relw,
                       const float* __restrict__ wfc, __bf16* __restrict__ wqkb,
                       __bf16* __restrict__ wvb, __bf16* __restrict__ rhb,
                       __bf16* __restrict__ rwb, __bf16* __restrict__ Wt,
                       float* __restrict__ zpad4) {
  const int bid = blockIdx.x, tid = threadIdx.x;
  if (bid < 2048) {
    int i = bid * 256 + tid;
    wqkb[i] = (__bf16)wqk[i];
  } else if (bid < 3072) {
    int i = (bid - 2048) * 256 + tid;
    wvb[i] = (__bf16)wv[i];
  } else if (bid < 3104) {
    int i = (bid - 3072) * 256 + tid;
    if (i < 8064) rhb[i] = (__bf16)relh[i];
  } else if (bid < 3136) {
    int i = (bid - 3104) * 256 + tid;
    if (i < 8064) rwb[i] = (__bf16)relw[i];
  } else if (bid < 4160) {
    int i = (bid - 3136) * 256 + tid;    // (o,c) pair
    const float* src = wfc + (size_t)i * 9;
#pragma unroll
    for (int tap = 0; tap < 9; ++tap)
      Wt[(size_t)tap * 262144 + i] = (__bf16)src[tap];
  } else {
    int i = (bid - 4160) * 256 + tid;
    f32x4 z = {0.f, 0.f, 0.f, 0.f};
    reinterpret_cast<f32x4*>(zpad4)[i] = z;
  }
}

// ------------------------------------------------------------------
// BN1 + ReLU on fp32 x, transpose (b,c,s) -> (b,s,c), bf16 out
// ------------------------------------------------------------------
__global__ void k_bn1(const float* __restrict__ x, const float* __restrict__ g,
                      const float* __restrict__ bb, const float* __restrict__ m,
                      const float* __restrict__ v, __bf16* __restrict__ y) {
  __shared__ float tile[32][33];
  const int b = blockIdx.z, c0 = blockIdx.y * 32, s0 = blockIdx.x * 32;
  const int tx = threadIdx.x, ty = threadIdx.y;   // 32 x 8
#pragma unroll
  for (int r = 0; r < 4; ++r) {
    int c = c0 + ty + r * 8;
    float inv = g[c] * rsqrtf(v[c] + 1e-5f);
    float beta = bb[c] - m[c] * inv;
    float val = x[((size_t)b * 512 + c) * 1024 + s0 + tx] * inv + beta;
    tile[ty + r * 8][tx] = fmaxf(val, 0.0f);
  }
  __syncthreads();
#pragma unroll
  for (int r = 0; r < 4; ++r) {
    int s = s0 + ty + r * 8;
    y[((size_t)b * 1024 + s) * 512 + c0 + tx] = (__bf16)tile[tx][ty + r * 8];
  }
}

// ------------------------------------------------------------------
// BN2 + split-K combine: x2 = (o0+o1)/(l0+l1) + x  (written in-place over
// o0, same flat index, per-thread read-before-write), then BN+ReLU ->
// padded (b,34,34,c) bf16. o1 lives in d_out (dead until k_sum).
// ------------------------------------------------------------------
__global__ void k_bn2c(float* o0x2, const float* __restrict__ o1,
                       const float* __restrict__ lp, const float* __restrict__ xin,
                       const float* __restrict__ g, const float* __restrict__ bb,
                       const float* __restrict__ m, const float* __restrict__ v,
                       __bf16* __restrict__ zp) {
  __shared__ float tile[32][33];
  const int b = blockIdx.z, c0 = blockIdx.y * 32, s0 = blockIdx.x * 32;
  const int tx = threadIdx.x, ty = threadIdx.y;
  const int bnrow = b * 4 + (c0 >> 7);     // c0..c0+31 stay in one 128-block
  const int scol = s0 + tx;
  const float linv =
      1.0f / (lp[bnrow * 1024 + scol] + lp[32768 + bnrow * 1024 + scol]);
#pragma unroll
  for (int r = 0; r < 4; ++r) {
    int c = c0 + ty + r * 8;
    float inv = g[c] * rsqrtf(v[c] + 1e-5f);
    float beta = bb[c] - m[c] * inv;
    size_t idx = ((size_t)b * 512 + c) * 1024 + scol;
    float t = (o0x2[idx] + o1[idx]) * linv + xin[idx];
    o0x2[idx] = t;                          // x2 for k_sum
    tile[ty + r * 8][tx] = fmaxf(t * inv + beta, 0.0f);
  }
  __syncthreads();
#pragma unroll
  for (int r = 0; r < 4; ++r) {
    int s = s0 + ty + r * 8;
    int hh = s >> 5, ww = s & 31;
    zp[(((size_t)b * 34 + hh + 1) * 34 + ww + 1) * 512 + c0 + tx] =
        (__bf16)tile[tx][ty + r * 8];
  }
}

// ------------------------------------------------------------------
// QKV projection, prefetch double-buffered (from r8, ~neutral).
// ------------------------------------------------------------------
__global__ __launch_bounds__(256) void k_proj(
    const __bf16* __restrict__ wall, const __bf16* __restrict__ y,
    __bf16* __restrict__ qout, __bf16* __restrict__ kout,
    __bf16* __restrict__ vout) {
  __shared__ __bf16 As[2][128 * 32];   // 16 KB
  __shared__ __bf16 Bs[2][128 * 32];   // 16 KB
  const int t = threadIdx.x;
  const int wave = t >> 6, lane = t & 63;
  const int l15 = lane & 15, quad = lane >> 4;
  const int mbase = blockIdx.x * 128;   // o in [0,1536)
  const int nbase = blockIdx.y * 128;   // flat (b,s)
  const int mh = (wave >> 1) * 64, nh = (wave & 1) * 64;
  const bool isv = mbase >= 1024;

  const int row0 = t >> 2, part8 = (t & 3) * 8;
  const __bf16* gA0 = wall + (size_t)(mbase + row0) * 512 + part8;
  const __bf16* gA1 = gA0 + (size_t)64 * 512;
  const __bf16* gB0 = y + (size_t)(nbase + row0) * 512 + part8;
  const __bf16* gB1 = gB0 + (size_t)64 * 512;
  const int wofs = wave * 512;

  const f32x4 fz = {0.f, 0.f, 0.f, 0.f};
  f32x4 acc[4][4];
#pragma unroll
  for (int i = 0; i < 4; ++i)
#pragma unroll
    for (int j = 0; j < 4; ++j) acc[i][j] = fz;

  // prologue: stage K-tile 0
  gld16(gA0, &As[0][wofs]);
  gld16(gA1, &As[0][2048 + wofs]);
  gld16(gB0, &Bs[0][wofs]);
  gld16(gB1, &Bs[0][2048 + wofs]);
  __syncthreads();

#pragma unroll 1
  for (int r = 0; r < 16; ++r) {
    const int cur = r & 1;
    if (r < 15) {
      const int kn = (r + 1) * 32;
      gld16(gA0 + kn, &As[cur ^ 1][wofs]);
      gld16(gA1 + kn, &As[cur ^ 1][2048 + wofs]);
      gld16(gB0 + kn, &Bs[cur ^ 1][wofs]);
      gld16(gB1 + kn, &Bs[cur ^ 1][2048 + wofs]);
    }
    v8bf a[4], bfr[4];
#pragma unroll
    for (int i = 0; i < 4; ++i)
      a[i] = load8(&As[cur][(mh + i * 16 + l15) * 32 + quad * 8]);
#pragma unroll
    for (int j = 0; j < 4; ++j)
      bfr[j] = load8(&Bs[cur][(nh + j * 16 + l15) * 32 + quad * 8]);
    if (isv) {
#pragma unroll
      for (int i = 0; i < 4; ++i)
#pragma unroll
        for (int j = 0; j < 4; ++j) acc[i][j] = mfma16(a[i], bfr[j], acc[i][j]);
    } else {
#pragma unroll
      for (int i = 0; i < 4; ++i)
#pragma unroll
        for (int j = 0; j < 4; ++j) acc[i][j] = mfma16(bfr[j], a[i], acc[i][j]);
    }
    __syncthreads();
  }

  if (isv) {
#pragma unroll
    for (int i = 0; i < 4; ++i)
#pragma unroll
      for (int j = 0; j < 4; ++j)
#pragma unroll
        for (int r = 0; r < 4; ++r) {
          int o = mbase + mh + i * 16 + quad * 4 + r;
          int nflat = nbase + nh + j * 16 + l15;
          int b = nflat >> 10, s = nflat & 1023;
          int oe = o - 1024; int n = oe >> 7, d = oe & 127;
          vout[(((size_t)b * 4 + n) * 128 + d) * 1024 + s] = (__bf16)acc[i][j][r];
        }
  } else {
    const bool isq = mbase < 512;
#pragma unroll
    for (int i = 0; i < 4; ++i)
#pragma unroll
      for (int j = 0; j < 4; ++j)
#pragma unroll
        for (int r = 0; r < 4; ++r) {
          int o = mbase + mh + i * 16 + l15;
          int nflat = nbase + nh + j * 16 + quad * 4 + r;
          int b = nflat >> 10, s = nflat & 1023;
          float val = acc[i][j][r];
          if (isq) {
            int n = o >> 7, d = o & 127;
            qout[(((size_t)b * 4 + n) * 1024 + s) * 128 + d] = (__bf16)(val * SCALE_Q);
          } else {
            int oe = o - 512; int n = oe >> 7, d = oe & 127;
            kout[(((size_t)b * 4 + n) * 1024 + s) * 128 + d] = (__bf16)val;
          }
        }
  }
}

// ------------------------------------------------------------------
// Flash attention v14 = r9's verified v12 (32 q-rows/wave, split-K=2,
// 512 blocks x 4 waves = 2 independent blocks/CU) + Vs DOUBLE-BUFFER:
// the bottom lgkmcnt(0)+barrier existed only for the Vs WAR hazard;
// V[t+1] now targets the other buffer, its WAR carried by next iter's
// top-barrier chain (readers finished a full iteration ago). 3->2
// barriers/iter. vmcnt ledger unchanged: top vmcnt(2) drains K_t
// (K oldest 2 of 4), mid vmcnt(0) drains V_t + makes Ks overwrite safe.
// LDS 49.9 KB, still 2 blocks/CU (grid-capped). r10's 1-block/CU fusion
// regressed (lockstep 8-wave barrier domain, no cross-block overlap).
// ------------------------------------------------------------------
__global__ __launch_bounds__(256, 2) void k_attn(
    const __bf16* __restrict__ q, const __bf16* __restrict__ kmat,
    const __bf16* __restrict__ vt, const __bf16* __restrict__ relh,
    const __bf16* __restrict__ relw, float* __restrict__ o0,
    float* __restrict__ o1, float* __restrict__ lpart) {
  __shared__ __bf16 Ks[32 * 128];        // 8 KB: 4 kk-chunks of [32 j][32 d]
  __shared__ __bf16 Vs[2][128 * 32];     // 16 KB: double-buffered [128 d][32 j]
  __shared__ __bf16 P[4 * 32 * 36];      // 9 KB, wave-private bands
  __shared__ __bf16 RWs[128][33];        // 8.4 KB, wave-private bands
  __shared__ __bf16 RHs[128][33];        // 8.4 KB, wave-private bands
  // total 49.9 KB

  const int Lb = blockIdx.x;             // 0..511
  const int xcd = Lb & 7, local = Lb >> 3;   // local 0..63
  const int bn = xcd * 4 + (local & 3);
  const int qblk = (local >> 2) & 7;     // 0..7 : 128 q-rows each
  const int half = local >> 5;           // 0..1 : key-range split
  const int s0 = qblk * 128;

  const int t = threadIdx.x;
  const int wave = t >> 6, lane = t & 63;
  const int l15 = lane & 15, quad = lane >> 4;
  const size_t hoff = ((size_t)bn) << 17;
  const int s0w = s0 + wave * 32;        // wave owns rows s0w..s0w+31
  const int h0w = s0w >> 5;              // = qblk*4 + wave (32-aligned span)
  const int j00 = half * 512;

  // staging source pointers (identical mapping to r5's verified v10)
  const __bf16* kgA =
      kmat + hoff + (size_t)((t >> 2) & 31) * 128 + (t >> 7) * 32 + (t & 3) * 8;
  const __bf16* vgA = vt + hoff + (size_t)(t >> 2) * 1024 + (t & 3) * 8;
  __bf16* kswA = Ks + wave * 512;        // + c*2048

  // issue first K/V tile -- latency hides under the bias prologue
#pragma unroll
  for (int c = 0; c < 2; ++c)
    gld16(kgA + (size_t)j00 * 128 + c * 64, kswA + c * 2048);
#pragma unroll
  for (int dh = 0; dh < 2; ++dh)
    gld16(vgA + (size_t)dh * 64 * 1024 + j00, Vs[0] + wave * 512 + dh * 2048);

  v8bf aq[2][4];
#pragma unroll
  for (int h = 0; h < 2; ++h) {
    const __bf16* qp = q + hoff + (size_t)(s0w + h * 16 + l15) * 128;
#pragma unroll
    for (int kk = 0; kk < 4; ++kk) aq[h][kk] = load8(qp + kk * 32 + quad * 8);
  }

#pragma unroll
  for (int h = 0; h < 2; ++h) {
#pragma unroll
    for (int nt = 0; nt < 4; ++nt) {     // RWs via shift-write
      int rr = nt * 16 + l15;
      const __bf16* bp = relw + (size_t)rr * 128;
      f32x4 acc = {0.f, 0.f, 0.f, 0.f};
#pragma unroll
      for (int kk = 0; kk < 4; ++kk)
        acc = mfma16(aq[h][kk], load8(bp + kk * 32 + quad * 8), acc);
#pragma unroll
      for (int r = 0; r < 4; ++r) {
        int row15 = quad * 4 + r;
        int wj = rr + h * 16 + row15 - 31;     // ww = h*16+row15 (s0w 32-aligned)
        if (wj >= 0 && wj < 32)
          RWs[wave * 32 + h * 16 + row15][wj] = (__bf16)acc[r];
      }
    }
#pragma unroll
    for (int nt = 0; nt < 2; ++nt) {     // RHs direct
      int hj = nt * 16 + l15;
      const __bf16* bp = relh + (size_t)(hj - h0w + 31) * 128;
      f32x4 acc = {0.f, 0.f, 0.f, 0.f};
#pragma unroll
      for (int kk = 0; kk < 4; ++kk)
        acc = mfma16(aq[h][kk], load8(bp + kk * 32 + quad * 8), acc);
#pragma unroll
      for (int r = 0; r < 4; ++r)
        RHs[wave * 32 + h * 16 + quad * 4 + r][hj] = (__bf16)acc[r];
    }
  }

  // rel-W bias is periodic in j (mod 32): hoist per-row values
  // (wave-private band, same wave wrote it -> in-order LDS, no barrier).
  float rwreg[2][4][2];
#pragma unroll
  for (int h = 0; h < 2; ++h)
#pragma unroll
    for (int r = 0; r < 4; ++r) {
      const int gi = wave * 32 + h * 16 + quad * 4 + r;
      rwreg[h][r][0] = (float)RWs[gi][l15];
      rwreg[h][r][1] = (float)RWs[gi][l15 + 16];
    }

  __syncthreads();   // bias tables visible; first K/V tile landed (vmcnt 0)

  const f32x4 fz = {0.f, 0.f, 0.f, 0.f};
  float lsum[2][4];
#pragma unroll
  for (int h = 0; h < 2; ++h)
#pragma unroll
    for (int r = 0; r < 4; ++r) lsum[h][r] = 0.f;
  f32x4 oacc[2][8];
#pragma unroll
  for (int h = 0; h < 2; ++h)
#pragma unroll
    for (int dt = 0; dt < 8; ++dt) oacc[h][dt] = fz;
  __bf16* Pw = P + wave * 32 * 36;

#pragma unroll 1
  for (int iter = 0; iter < 16; ++iter) {
    // top: K_t ready-gate (outstanding: K_t oldest 2, V_t newest 2).
    asm volatile("s_waitcnt vmcnt(2)" ::: "memory");
    __builtin_amdgcn_s_barrier();
    __builtin_amdgcn_sched_barrier(0);

    // K fragments -> regs once, reused by both q-row tiles (h=0,1)
    v8bf kf[8];
#pragma unroll
    for (int nj = 0; nj < 2; ++nj)
#pragma unroll
      for (int kk = 0; kk < 4; ++kk)
        kf[nj * 4 + kk] =
            load8(&Ks[kk * 1024 + (nj * 16 + l15) * 32 + quad * 8]);

    // QK^T (16 MFMA covering 32q x 32j)
    f32x4 sacc[2][2];
    __builtin_amdgcn_s_setprio(1);
#pragma unroll
    for (int h = 0; h < 2; ++h)
#pragma unroll
      for (int nj = 0; nj < 2; ++nj) {
        f32x4 a = fz;
#pragma unroll
        for (int kk = 0; kk < 4; ++kk)
          a = mfma16(aq[h][kk], kf[nj * 4 + kk], a);
        sacc[h][nj] = a;
      }
    __builtin_amdgcn_s_setprio(0);

    // bias + exp(c=0) + partial l + stash P (wave-private band)
    const int hjb = half * 16 + iter;
#pragma unroll
    for (int h = 0; h < 2; ++h)
#pragma unroll
      for (int r = 0; r < 4; ++r) {
        const int row = h * 16 + quad * 4 + r;      // wave-local row
        const float rh0 = (float)RHs[wave * 32 + row][hjb];
#pragma unroll
        for (int nj = 0; nj < 2; ++nj) {
          float val = sacc[h][nj][r] + rwreg[h][r][nj] + rh0;
          float p = __expf(fminf(val, 60.0f));
          lsum[h][r] += p;
          Pw[row * 36 + nj * 16 + l15] = (__bf16)p;
        }
      }
    v8bf pf[2];
#pragma unroll
    for (int h = 0; h < 2; ++h)
      pf[h] = *reinterpret_cast<const v8bf*>(&Pw[(h * 16 + l15) * 36 + quad * 8]);

    // mid: V_t ready-gate; all waves past QK^T -> Ks overwrite safe.
    asm volatile("s_waitcnt vmcnt(0)" ::: "memory");
    __builtin_amdgcn_s_barrier();
    __builtin_amdgcn_sched_barrier(0);

    // issue K[t+1] (covered by PV phase below)
    if (iter < 15) {
      const int jn = j00 + (iter + 1) * 32;
#pragma unroll
      for (int c = 0; c < 2; ++c)
        gld16(kgA + (size_t)jn * 128 + c * 64, kswA + c * 2048);
    }

    // PV as O^T = V * P^T (16 MFMA): V-frag read once, used by both h.
    const __bf16* vcur = Vs[iter & 1];
    __builtin_amdgcn_s_setprio(1);
#pragma unroll
    for (int dt = 0; dt < 8; ++dt) {
      v8bf vf = load8(&vcur[(dt * 16 + l15) * 32 + quad * 8]);
#pragma unroll
      for (int h = 0; h < 2; ++h)
        oacc[h][dt] = mfma16(vf, pf[h], oacc[h][dt]);
    }
    __builtin_amdgcn_s_setprio(0);

    // V[t+1] -> other buffer: NO barrier needed (WAR carried by next
    // iteration's top-barrier chain; readers of that buffer finished a
    // full iteration ago). sched_barrier pins issue after PV reads.
    if (iter < 15) {
      __builtin_amdgcn_sched_barrier(0);
      const int jn = j00 + (iter + 1) * 32;
      __bf16* vnext = Vs[(iter + 1) & 1] + wave * 512;
#pragma unroll
      for (int dh = 0; dh < 2; ++dh)
        gld16(vgA + (size_t)dh * 64 * 1024 + jn, vnext + dh * 2048);
    }
  }

  // partial l: reduce across the 16-lane groups, store per-row by l15==0
#pragma unroll
  for (int h = 0; h < 2; ++h)
#pragma unroll
    for (int r = 0; r < 4; ++r) {
#pragma unroll
      for (int msk = 8; msk >= 1; msk >>= 1)
        lsum[h][r] += __shfl_xor(lsum[h][r], msk);
    }
  if (l15 == 0) {
#pragma unroll
    for (int h = 0; h < 2; ++h)
#pragma unroll
      for (int r = 0; r < 4; ++r)
        lpart[half * 32768 + bn * 1024 + s0w + h * 16 + quad * 4 + r] =
            lsum[h][r];
  }

  // partial O store (unnormalized): lane = query s -> coalesced
  {
    float* op = half ? o1 : o0;
#pragma unroll
    for (int h = 0; h < 2; ++h) {
      const int s = s0w + h * 16 + l15;
#pragma unroll
      for (int dt = 0; dt < 8; ++dt)
#pragma unroll
        for (int r = 0; r < 4; ++r) {
          int d = dt * 16 + quad * 4 + r;
          op[((size_t)bn * 128 + d) * 1024 + s] = oacc[h][dt][r];
        }
    }
  }
}

// ------------------------------------------------------------------
// 3x3 conv (r9 verified): BK=128 two-barrier + XCD chunked swizzle.
// ------------------------------------------------------------------
__global__ __launch_bounds__(256, 2) void k_conv(
    const __bf16* __restrict__ Wt, const __bf16* __restrict__ zp,
    float* __restrict__ part) {
  __shared__ __bf16 As[4 * 128 * 32];   // 32 KB
  __shared__ __bf16 Bs[4 * 128 * 32];   // 32 KB
  const int t = threadIdx.x;
  const int wave = t >> 6, lane = t & 63;
  const int l15 = lane & 15, quad = lane >> 4;

  const int Lb = blockIdx.x;            // 0..511
  const int logical = (Lb & 7) * 64 + (Lb >> 3);   // XCD-chunked (bijective)
  const int combo = logical & 7;
  const int ot = combo >> 1, sp = combo & 1;
  const int nt = logical >> 3;          // 8 contiguous nt per XCD = 1 batch
  const int mbase = ot * 128;
  const int nbase = nt * 128;
  const int cs = sp * 256;
  const int mh = (wave >> 1) * 64, nh = (wave & 1) * 64;

  const int row0 = t >> 2;
  const int part8 = (t & 3) * 8;
  const __bf16* gA0 = Wt + (size_t)(mbase + row0) * 512 + cs + part8;
  const __bf16* gA1 = gA0 + (size_t)64 * 512;
  const int n0 = nbase + row0;
  const int b0 = n0 >> 10, spn = n0 & 1023;
  const __bf16* gB0 =
      zp + ((size_t)(b0 * 34 + (spn >> 5) + 1) * 34 + (spn & 31) + 1) * 512 + cs + part8;
  const __bf16* gB1 = gB0 + (size_t)2 * 34 * 512;
  const int wofs = wave * 512;

  const f32x4 fz = {0.f, 0.f, 0.f, 0.f};
  f32x4 acc[4][4];
#pragma unroll
  for (int i = 0; i < 4; ++i)
#pragma unroll
    for (int j = 0; j < 4; ++j) acc[i][j] = fz;

#pragma unroll 1
  for (int tap = 0; tap < 9; ++tap) {
    const int dh = tap / 3 - 1, dw = tap % 3 - 1;
    const size_t aoff = (size_t)tap * 512 * 512;
    const int boff = (dh * 34 + dw) * 512;
#pragma unroll 1
    for (int k0 = 0; k0 < 256; k0 += 128) {
      __syncthreads();
#pragma unroll
      for (int c = 0; c < 4; ++c) {
        const int kq = k0 + c * 32;
        gld16(gA0 + aoff + kq, As + c * 4096 + wofs);
        gld16(gA1 + aoff + kq, As + c * 4096 + 2048 + wofs);
        gld16(gB0 + boff + kq, Bs + c * 4096 + wofs);
        gld16(gB1 + boff + kq, Bs + c * 4096 + 2048 + wofs);
      }
      __syncthreads();
#pragma unroll
      for (int c = 0; c < 4; ++c) {
        v8bf a[4], bfr[4];
#pragma unroll
        for (int i = 0; i < 4; ++i)
          a[i] = load8(&As[c * 4096 + (mh + i * 16 + l15) * 32 + quad * 8]);
#pragma unroll
        for (int j = 0; j < 4; ++j)
          bfr[j] = load8(&Bs[c * 4096 + (nh + j * 16 + l15) * 32 + quad * 8]);
#pragma unroll
        for (int i = 0; i < 4; ++i)
#pragma unroll
          for (int j = 0; j < 4; ++j) acc[i][j] = mfma16(a[i], bfr[j], acc[i][j]);
      }
    }
  }

  float* pout = part + (size_t)sp * 8 * 512 * 1024;
#pragma unroll
  for (int i = 0; i < 4; ++i)
#pragma unroll
    for (int j = 0; j < 4; ++j)
#pragma unroll
      for (int r = 0; r < 4; ++r) {
        int o = mbase + mh + i * 16 + quad * 4 + r;
        int nn = nbase + nh + j * 16 + l15;
        int bb2 = nn >> 10, s = nn & 1023;
        pout[((size_t)bb2 * 512 + o) * 1024 + s] = acc[i][j][r];
      }
}

// ------------------------------------------------------------------
// out = part0 + part1 + bias + x2   (f32x4 vectorized)
// ------------------------------------------------------------------
__global__ void k_sum(const float* __restrict__ part, const float* __restrict__ bias,
                      const float* __restrict__ x2, float* __restrict__ out) {
  int i = blockIdx.x * 256 + threadIdx.x;
  int o = (i >> 8) & 511;
  f32x4 p0 = reinterpret_cast<const f32x4*>(part)[i];
  f32x4 p1 = reinterpret_cast<const f32x4*>(part + (size_t)8 * 512 * 1024)[i];
  f32x4 xr = reinterpret_cast<const f32x4*>(x2)[i];
  float bo = bias[o];
  f32x4 r;
#pragma unroll
  for (int c = 0; c < 4; ++c) r[c] = p0[c] + p1[c] + bo + xr[c];
  reinterpret_cast<f32x4*>(out)[i] = r;
}

// ------------------------------------------------------------------
extern "C" void kernel_launch(void* const* d_in, const int* in_sizes, int n_in,
                              void* d_out, int out_size, void* d_ws, size_t ws_size,
                              hipStream_t stream) {
  const float* x    = (const float*)d_in[0];
  const float* wqk  = (const float*)d_in[1];
  const float* wv   = (const float*)d_in[2];
  const float* relh = (const float*)d_in[3];
  const float* relw = (const float*)d_in[4];
  const float* g1   = (const float*)d_in[5];
  const float* b1   = (const float*)d_in[6];
  const float* m1   = (const float*)d_in[7];
  const float* v1   = (const float*)d_in[8];
  const float* g2   = (const float*)d_in[9];
  const float* b2   = (const float*)d_in[10];
  const float* m2   = (const float*)d_in[11];
  const float* v2   = (const float*)d_in[12];
  const float* wfc  = (const float*)d_in[13];
  const float* bfc  = (const float*)d_in[14];
  float* out = (float*)d_out;

  char* p = (char*)d_ws;
  __bf16* y    = (__bf16*)p; p += (size_t)8 * 1024 * 512 * 2;       // (b,s,c)
  __bf16* qb   = (__bf16*)p; p += (size_t)8 * 4 * 1024 * 128 * 2;   // (b,n,s,d)
  __bf16* kb   = (__bf16*)p; p += (size_t)8 * 4 * 1024 * 128 * 2;   // (b,n,s,d)
  __bf16* vb   = (__bf16*)p; p += (size_t)8 * 4 * 1024 * 128 * 2;   // (b,n,d,s)
  __bf16* Wt   = (__bf16*)p; p += (size_t)9 * 512 * 512 * 2;        // (tap,o,c)
  __bf16* wqkb = (__bf16*)p; p += (size_t)1024 * 512 * 2;           // wall rows 0..1023
  __bf16* wvb  = (__bf16*)p; p += (size_t)512 * 512 * 2;            // wall rows 1024..1535
  __bf16* rhb  = (__bf16*)p; p += 32768;
  __bf16* rwb  = (__bf16*)p; p += 32768;
  float*  x2   = (float*)p;  p += (size_t)8 * 512 * 1024 * 4;       // o0 -> x2 (b,c,s) fp32
  __bf16* zpad = (__bf16*)p; p += (size_t)8 * 34 * 34 * 512 * 2;    // padded z
  // scratch aliases (live ranges disjoint):
  //   lpart: y region (y dead after k_proj; k_attn writes, k_bn2c reads,
  //          then k_conv's part overwrites)
  //   o1   : d_out (dead until k_sum writes it)
  //   part : d_ws base (y..vb dead after k_attn/k_bn2c)
  float* lpart = (float*)d_ws;
  float* o0 = x2;
  float* o1 = (float*)d_out;
  float* part = (float*)d_ws;

  k_prep<<<dim3(6472), dim3(256), 0, stream>>>(wqk, wv, relh, relw, wfc,
                                               wqkb, wvb, rhb, rwb, Wt, (float*)zpad);
  k_bn1<<<dim3(32, 16, 8), dim3(32, 8), 0, stream>>>(x, g1, b1, m1, v1, y);
  k_proj<<<dim3(12, 64), dim3(256), 0, stream>>>(wqkb, y, qb, kb, vb);
  k_attn<<<dim3(512), dim3(256), 0, stream>>>(qb, kb, vb, rhb, rwb, o0, o1, lpart);
  k_bn2c<<<dim3(32, 16, 8), dim3(32, 8), 0, stream>>>(o0, o1, lpart, x,
                                                      g2, b2, m2, v2, zpad);
  k_conv<<<dim3(512), dim3(256), 0, stream>>>(Wt, zpad, part);
  k_sum<<<dim3(4096), dim3(256), 0, stream>>>(part, bfc, x2, out);
}

// Round 12
// 237.458 us; speedup vs baseline: 1.0673x; 1.0224x over previous
//
#include <hip/hip_runtime.h>

typedef __bf16 v8bf __attribute__((ext_vector_type(8)));
typedef float f32x4 __attribute__((ext_vector_type(4)));

#define DEVI static __device__ __forceinline__

DEVI v8bf load8(const __bf16* p) { return *reinterpret_cast<const v8bf*>(p); }

DEVI f32x4 mfma16(v8bf a, v8bf b, f32x4 c) {
  return __builtin_amdgcn_mfma_f32_16x16x32_bf16(a, b, c, 0, 0, 0);
}

// async global -> LDS, 16 bytes per lane. LDS dest: wave-uniform base + lane*16.
DEVI void gld16(const __bf16* g, __bf16* l) {
  __builtin_amdgcn_global_load_lds(
      (const __attribute__((address_space(1))) unsigned int*)(const void*)g,
      (__attribute__((address_space(3))) unsigned int*)(void*)l, 16, 0, 0);
}

#define SCALE_Q 0.08838834764831845f  // 128^-0.5

// ------------------------------------------------------------------
// Fused prologue: casts, conv-weight repack, zpad zero, BN1+ReLU
// transpose (absorbed k_bn1: blocks 6472..10567). One launch.
// ------------------------------------------------------------------
__global__ void k_prep(const float* __restrict__ wqk, const float* __restrict__ wv,
                       const float* __restrict__ relh, const float* __restrict__ relw,
                       const float* __restrict__ wfc, __bf16* __restrict__ wqkb,
                       __bf16* __restrict__ wvb, __bf16* __restrict__ rhb,
                       __bf16* __restrict__ rwb, __bf16* __restrict__ Wt,
                       float* __restrict__ zpad4, const float* __restrict__ x,
                       const float* __restrict__ g1, const float* __restrict__ b1,
                       const float* __restrict__ m1, const float* __restrict__ v1,
                       __bf16* __restrict__ y) {
  __shared__ float tile[32][33];
  const int bid = blockIdx.x, tid = threadIdx.x;
  if (bid >= 6472) {
    // ---- BN1 + ReLU + transpose (b,c,s) -> (b,s,c) bf16 ----
    const int local = bid - 6472;              // 0..4095
    const int b = local >> 9, c0 = ((local >> 5) & 15) * 32, s0 = (local & 31) * 32;
    const int tx = tid & 31, ty = tid >> 5;    // 32 x 8
#pragma unroll
    for (int r = 0; r < 4; ++r) {
      int c = c0 + ty + r * 8;
      float inv = g1[c] * rsqrtf(v1[c] + 1e-5f);
      float beta = b1[c] - m1[c] * inv;
      float val = x[((size_t)b * 512 + c) * 1024 + s0 + tx] * inv + beta;
      tile[ty + r * 8][tx] = fmaxf(val, 0.0f);
    }
    __syncthreads();
#pragma unroll
    for (int r = 0; r < 4; ++r) {
      int s = s0 + ty + r * 8;
      y[((size_t)b * 1024 + s) * 512 + c0 + tx] = (__bf16)tile[tx][ty + r * 8];
    }
    return;
  }
  if (bid < 2048) {
    int i = bid * 256 + tid;
    wqkb[i] = (__bf16)wqk[i];
  } else if (bid < 3072) {
    int i = (bid - 2048) * 256 + tid;
    wvb[i] = (__bf16)wv[i];
  } else if (bid < 3104) {
    int i = (bid - 3072) * 256 + tid;
    if (i < 8064) rhb[i] = (__bf16)relh[i];
  } else if (bid < 3136) {
    int i = (bid - 3104) * 256 + tid;
    if (i < 8064) rwb[i] = (__bf16)relw[i];
  } else if (bid < 4160) {
    int i = (bid - 3136) * 256 + tid;    // (o,c) pair
    const float* src = wfc + (size_t)i * 9;
#pragma unroll
    for (int tap = 0; tap < 9; ++tap)
      Wt[(size_t)tap * 262144 + i] = (__bf16)src[tap];
  } else {
    int i = (bid - 4160) * 256 + tid;
    f32x4 z = {0.f, 0.f, 0.f, 0.f};
    reinterpret_cast<f32x4*>(zpad4)[i] = z;
  }
}

// ------------------------------------------------------------------
// BN2 + split-K combine: x2 = (o0+o1)/(l0+l1) + x  (written in-place over
// o0, same flat index, per-thread read-before-write), then BN+ReLU ->
// padded (b,34,34,c) bf16. o1 lives in d_out (dead until k_sum).
// ------------------------------------------------------------------
__global__ void k_bn2c(float* o0x2, const float* __restrict__ o1,
                       const float* __restrict__ lp, const float* __restrict__ xin,
                       const float* __restrict__ g, const float* __restrict__ bb,
                       const float* __restrict__ m, const float* __restrict__ v,
                       __bf16* __restrict__ zp) {
  __shared__ float tile[32][33];
  const int b = blockIdx.z, c0 = blockIdx.y * 32, s0 = blockIdx.x * 32;
  const int tx = threadIdx.x, ty = threadIdx.y;
  const int bnrow = b * 4 + (c0 >> 7);     // c0..c0+31 stay in one 128-block
  const int scol = s0 + tx;
  const float linv =
      1.0f / (lp[bnrow * 1024 + scol] + lp[32768 + bnrow * 1024 + scol]);
#pragma unroll
  for (int r = 0; r < 4; ++r) {
    int c = c0 + ty + r * 8;
    float inv = g[c] * rsqrtf(v[c] + 1e-5f);
    float beta = bb[c] - m[c] * inv;
    size_t idx = ((size_t)b * 512 + c) * 1024 + scol;
    float t = (o0x2[idx] + o1[idx]) * linv + xin[idx];
    o0x2[idx] = t;                          // x2 for k_sum
    tile[ty + r * 8][tx] = fmaxf(t * inv + beta, 0.0f);
  }
  __syncthreads();
#pragma unroll
  for (int r = 0; r < 4; ++r) {
    int s = s0 + ty + r * 8;
    int hh = s >> 5, ww = s & 31;
    zp[(((size_t)b * 34 + hh + 1) * 34 + ww + 1) * 512 + c0 + tx] =
        (__bf16)tile[tx][ty + r * 8];
  }
}

// ------------------------------------------------------------------
// QKV projection, prefetch double-buffered + XCD-chunked swizzle:
// 1-D grid 768; logical=(Lb&7)*96+(Lb>>3) -> each XCD owns 8 contiguous
// n-tiles x all 12 m-tiles (y slice 1 MB + weights 1.5 MB, L2-resident).
// Was: blockIdx.x fastest -> 12 same-y sharers sprayed over 8 XCDs ->
// up to 8x y re-fetch (the same pathology conv's swizzle fixed in r8).
// ------------------------------------------------------------------
__global__ __launch_bounds__(256) void k_proj(
    const __bf16* __restrict__ wall, const __bf16* __restrict__ y,
    __bf16* __restrict__ qout, __bf16* __restrict__ kout,
    __bf16* __restrict__ vout) {
  __shared__ __bf16 As[2][128 * 32];   // 16 KB
  __shared__ __bf16 Bs[2][128 * 32];   // 16 KB
  const int t = threadIdx.x;
  const int wave = t >> 6, lane = t & 63;
  const int l15 = lane & 15, quad = lane >> 4;
  const int Lb = blockIdx.x;            // 0..767
  const int logical = (Lb & 7) * 96 + (Lb >> 3);   // bijective
  const int nt = logical / 12, mt = logical % 12;
  const int mbase = mt * 128;           // o in [0,1536)
  const int nbase = nt * 128;           // flat (b,s)
  const int mh = (wave >> 1) * 64, nh = (wave & 1) * 64;
  const bool isv = mbase >= 1024;

  const int row0 = t >> 2, part8 = (t & 3) * 8;
  const __bf16* gA0 = wall + (size_t)(mbase + row0) * 512 + part8;
  const __bf16* gA1 = gA0 + (size_t)64 * 512;
  const __bf16* gB0 = y + (size_t)(nbase + row0) * 512 + part8;
  const __bf16* gB1 = gB0 + (size_t)64 * 512;
  const int wofs = wave * 512;

  const f32x4 fz = {0.f, 0.f, 0.f, 0.f};
  f32x4 acc[4][4];
#pragma unroll
  for (int i = 0; i < 4; ++i)
#pragma unroll
    for (int j = 0; j < 4; ++j) acc[i][j] = fz;

  // prologue: stage K-tile 0
  gld16(gA0, &As[0][wofs]);
  gld16(gA1, &As[0][2048 + wofs]);
  gld16(gB0, &Bs[0][wofs]);
  gld16(gB1, &Bs[0][2048 + wofs]);
  __syncthreads();

#pragma unroll 1
  for (int r = 0; r < 16; ++r) {
    const int cur = r & 1;
    if (r < 15) {
      const int kn = (r + 1) * 32;
      gld16(gA0 + kn, &As[cur ^ 1][wofs]);
      gld16(gA1 + kn, &As[cur ^ 1][2048 + wofs]);
      gld16(gB0 + kn, &Bs[cur ^ 1][wofs]);
      gld16(gB1 + kn, &Bs[cur ^ 1][2048 + wofs]);
    }
    v8bf a[4], bfr[4];
#pragma unroll
    for (int i = 0; i < 4; ++i)
      a[i] = load8(&As[cur][(mh + i * 16 + l15) * 32 + quad * 8]);
#pragma unroll
    for (int j = 0; j < 4; ++j)
      bfr[j] = load8(&Bs[cur][(nh + j * 16 + l15) * 32 + quad * 8]);
    if (isv) {
#pragma unroll
      for (int i = 0; i < 4; ++i)
#pragma unroll
        for (int j = 0; j < 4; ++j) acc[i][j] = mfma16(a[i], bfr[j], acc[i][j]);
    } else {
#pragma unroll
      for (int i = 0; i < 4; ++i)
#pragma unroll
        for (int j = 0; j < 4; ++j) acc[i][j] = mfma16(bfr[j], a[i], acc[i][j]);
    }
    __syncthreads();
  }

  if (isv) {
#pragma unroll
    for (int i = 0; i < 4; ++i)
#pragma unroll
      for (int j = 0; j < 4; ++j)
#pragma unroll
        for (int r = 0; r < 4; ++r) {
          int o = mbase + mh + i * 16 + quad * 4 + r;
          int nflat = nbase + nh + j * 16 + l15;
          int b = nflat >> 10, s = nflat & 1023;
          int oe = o - 1024; int n = oe >> 7, d = oe & 127;
          vout[(((size_t)b * 4 + n) * 128 + d) * 1024 + s] = (__bf16)acc[i][j][r];
        }
  } else {
    const bool isq = mbase < 512;
#pragma unroll
    for (int i = 0; i < 4; ++i)
#pragma unroll
      for (int j = 0; j < 4; ++j)
#pragma unroll
        for (int r = 0; r < 4; ++r) {
          int o = mbase + mh + i * 16 + l15;
          int nflat = nbase + nh + j * 16 + quad * 4 + r;
          int b = nflat >> 10, s = nflat & 1023;
          float val = acc[i][j][r];
          if (isq) {
            int n = o >> 7, d = o & 127;
            qout[(((size_t)b * 4 + n) * 1024 + s) * 128 + d] = (__bf16)(val * SCALE_Q);
          } else {
            int oe = o - 512; int n = oe >> 7, d = oe & 127;
            kout[(((size_t)b * 4 + n) * 1024 + s) * 128 + d] = (__bf16)val;
          }
        }
  }
}

// ------------------------------------------------------------------
// Flash attention v14 (r11, passed): 32 q-rows/wave, split-K=2, Vs
// double-buffered (2 barriers/iter), conflicts 4.4M->2.3M.
// ------------------------------------------------------------------
__global__ __launch_bounds__(256, 2) void k_attn(
    const __bf16* __restrict__ q, const __bf16* __restrict__ kmat,
    const __bf16* __restrict__ vt, const __bf16* __restrict__ relh,
    const __bf16* __restrict__ relw, float* __restrict__ o0,
    float* __restrict__ o1, float* __restrict__ lpart) {
  __shared__ __bf16 Ks[32 * 128];        // 8 KB: 4 kk-chunks of [32 j][32 d]
  __shared__ __bf16 Vs[2][128 * 32];     // 16 KB: double-buffered [128 d][32 j]
  __shared__ __bf16 P[4 * 32 * 36];      // 9 KB, wave-private bands
  __shared__ __bf16 RWs[128][33];        // 8.4 KB, wave-private bands
  __shared__ __bf16 RHs[128][33];        // 8.4 KB, wave-private bands
  // total 49.9 KB

  const int Lb = blockIdx.x;             // 0..511
  const int xcd = Lb & 7, local = Lb >> 3;   // local 0..63
  const int bn = xcd * 4 + (local & 3);
  const int qblk = (local >> 2) & 7;     // 0..7 : 128 q-rows each
  const int half = local >> 5;           // 0..1 : key-range split
  const int s0 = qblk * 128;

  const int t = threadIdx.x;
  const int wave = t >> 6, lane = t & 63;
  const int l15 = lane & 15, quad = lane >> 4;
  const size_t hoff = ((size_t)bn) << 17;
  const int s0w = s0 + wave * 32;        // wave owns rows s0w..s0w+31
  const int h0w = s0w >> 5;              // = qblk*4 + wave (32-aligned span)
  const int j00 = half * 512;

  // staging source pointers (identical mapping to r5's verified v10)
  const __bf16* kgA =
      kmat + hoff + (size_t)((t >> 2) & 31) * 128 + (t >> 7) * 32 + (t & 3) * 8;
  const __bf16* vgA = vt + hoff + (size_t)(t >> 2) * 1024 + (t & 3) * 8;
  __bf16* kswA = Ks + wave * 512;        // + c*2048

  // issue first K/V tile -- latency hides under the bias prologue
#pragma unroll
  for (int c = 0; c < 2; ++c)
    gld16(kgA + (size_t)j00 * 128 + c * 64, kswA + c * 2048);
#pragma unroll
  for (int dh = 0; dh < 2; ++dh)
    gld16(vgA + (size_t)dh * 64 * 1024 + j00, Vs[0] + wave * 512 + dh * 2048);

  v8bf aq[2][4];
#pragma unroll
  for (int h = 0; h < 2; ++h) {
    const __bf16* qp = q + hoff + (size_t)(s0w + h * 16 + l15) * 128;
#pragma unroll
    for (int kk = 0; kk < 4; ++kk) aq[h][kk] = load8(qp + kk * 32 + quad * 8);
  }

#pragma unroll
  for (int h = 0; h < 2; ++h) {
#pragma unroll
    for (int nt = 0; nt < 4; ++nt) {     // RWs via shift-write
      int rr = nt * 16 + l15;
      const __bf16* bp = relw + (size_t)rr * 128;
      f32x4 acc = {0.f, 0.f, 0.f, 0.f};
#pragma unroll
      for (int kk = 0; kk < 4; ++kk)
        acc = mfma16(aq[h][kk], load8(bp + kk * 32 + quad * 8), acc);
#pragma unroll
      for (int r = 0; r < 4; ++r) {
        int row15 = quad * 4 + r;
        int wj = rr + h * 16 + row15 - 31;     // ww = h*16+row15 (s0w 32-aligned)
        if (wj >= 0 && wj < 32)
          RWs[wave * 32 + h * 16 + row15][wj] = (__bf16)acc[r];
      }
    }
#pragma unroll
    for (int nt = 0; nt < 2; ++nt) {     // RHs direct
      int hj = nt * 16 + l15;
      const __bf16* bp = relh + (size_t)(hj - h0w + 31) * 128;
      f32x4 acc = {0.f, 0.f, 0.f, 0.f};
#pragma unroll
      for (int kk = 0; kk < 4; ++kk)
        acc = mfma16(aq[h][kk], load8(bp + kk * 32 + quad * 8), acc);
#pragma unroll
      for (int r = 0; r < 4; ++r)
        RHs[wave * 32 + h * 16 + quad * 4 + r][hj] = (__bf16)acc[r];
    }
  }

  // rel-W bias is periodic in j (mod 32): hoist per-row values
  // (wave-private band, same wave wrote it -> in-order LDS, no barrier).
  float rwreg[2][4][2];
#pragma unroll
  for (int h = 0; h < 2; ++h)
#pragma unroll
    for (int r = 0; r < 4; ++r) {
      const int gi = wave * 32 + h * 16 + quad * 4 + r;
      rwreg[h][r][0] = (float)RWs[gi][l15];
      rwreg[h][r][1] = (float)RWs[gi][l15 + 16];
    }

  __syncthreads();   // bias tables visible; first K/V tile landed (vmcnt 0)

  const f32x4 fz = {0.f, 0.f, 0.f, 0.f};
  float lsum[2][4];
#pragma unroll
  for (int h = 0; h < 2; ++h)
#pragma unroll
    for (int r = 0; r < 4; ++r) lsum[h][r] = 0.f;
  f32x4 oacc[2][8];
#pragma unroll
  for (int h = 0; h < 2; ++h)
#pragma unroll
    for (int dt = 0; dt < 8; ++dt) oacc[h][dt] = fz;
  __bf16* Pw = P + wave * 32 * 36;

#pragma unroll 1
  for (int iter = 0; iter < 16; ++iter) {
    // top: K_t ready-gate (outstanding: K_t oldest 2, V_t newest 2).
    asm volatile("s_waitcnt vmcnt(2)" ::: "memory");
    __builtin_amdgcn_s_barrier();
    __builtin_amdgcn_sched_barrier(0);

    // K fragments -> regs once, reused by both q-row tiles (h=0,1)
    v8bf kf[8];
#pragma unroll
    for (int nj = 0; nj < 2; ++nj)
#pragma unroll
      for (int kk = 0; kk < 4; ++kk)
        kf[nj * 4 + kk] =
            load8(&Ks[kk * 1024 + (nj * 16 + l15) * 32 + quad * 8]);

    // QK^T (16 MFMA covering 32q x 32j)
    f32x4 sacc[2][2];
    __builtin_amdgcn_s_setprio(1);
#pragma unroll
    for (int h = 0; h < 2; ++h)
#pragma unroll
      for (int nj = 0; nj < 2; ++nj) {
        f32x4 a = fz;
#pragma unroll
        for (int kk = 0; kk < 4; ++kk)
          a = mfma16(aq[h][kk], kf[nj * 4 + kk], a);
        sacc[h][nj] = a;
      }
    __builtin_amdgcn_s_setprio(0);

    // bias + exp(c=0) + partial l + stash P (wave-private band)
    const int hjb = half * 16 + iter;
#pragma unroll
    for (int h = 0; h < 2; ++h)
#pragma unroll
      for (int r = 0; r < 4; ++r) {
        const int row = h * 16 + quad * 4 + r;      // wave-local row
        const float rh0 = (float)RHs[wave * 32 + row][hjb];
#pragma unroll
        for (int nj = 0; nj < 2; ++nj) {
          float val = sacc[h][nj][r] + rwreg[h][r][nj] + rh0;
          float p = __expf(fminf(val, 60.0f));
          lsum[h][r] += p;
          Pw[row * 36 + nj * 16 + l15] = (__bf16)p;
        }
      }
    v8bf pf[2];
#pragma unroll
    for (int h = 0; h < 2; ++h)
      pf[h] = *reinterpret_cast<const v8bf*>(&Pw[(h * 16 + l15) * 36 + quad * 8]);

    // mid: V_t ready-gate; all waves past QK^T -> Ks overwrite safe.
    asm volatile("s_waitcnt vmcnt(0)" ::: "memory");
    __builtin_amdgcn_s_barrier();
    __builtin_amdgcn_sched_barrier(0);

    // issue K[t+1] (covered by PV phase below)
    if (iter < 15) {
      const int jn = j00 + (iter + 1) * 32;
#pragma unroll
      for (int c = 0; c < 2; ++c)
        gld16(kgA + (size_t)jn * 128 + c * 64, kswA + c * 2048);
    }

    // PV as O^T = V * P^T (16 MFMA): V-frag read once, used by both h.
    const __bf16* vcur = Vs[iter & 1];
    __builtin_amdgcn_s_setprio(1);
#pragma unroll
    for (int dt = 0; dt < 8; ++dt) {
      v8bf vf = load8(&vcur[(dt * 16 + l15) * 32 + quad * 8]);
#pragma unroll
      for (int h = 0; h < 2; ++h)
        oacc[h][dt] = mfma16(vf, pf[h], oacc[h][dt]);
    }
    __builtin_amdgcn_s_setprio(0);

    // V[t+1] -> other buffer: WAR carried by next iteration's top-barrier
    // chain (readers of that buffer finished a full iteration ago).
    if (iter < 15) {
      __builtin_amdgcn_sched_barrier(0);
      const int jn = j00 + (iter + 1) * 32;
      __bf16* vnext = Vs[(iter + 1) & 1] + wave * 512;
#pragma unroll
      for (int dh = 0; dh < 2; ++dh)
        gld16(vgA + (size_t)dh * 64 * 1024 + jn, vnext + dh * 2048);
    }
  }

  // partial l: reduce across the 16-lane groups, store per-row by l15==0
#pragma unroll
  for (int h = 0; h < 2; ++h)
#pragma unroll
    for (int r = 0; r < 4; ++r) {
#pragma unroll
      for (int msk = 8; msk >= 1; msk >>= 1)
        lsum[h][r] += __shfl_xor(lsum[h][r], msk);
    }
  if (l15 == 0) {
#pragma unroll
    for (int h = 0; h < 2; ++h)
#pragma unroll
      for (int r = 0; r < 4; ++r)
        lpart[half * 32768 + bn * 1024 + s0w + h * 16 + quad * 4 + r] =
            lsum[h][r];
  }

  // partial O store (unnormalized): lane = query s -> coalesced
  {
    float* op = half ? o1 : o0;
#pragma unroll
    for (int h = 0; h < 2; ++h) {
      const int s = s0w + h * 16 + l15;
#pragma unroll
      for (int dt = 0; dt < 8; ++dt)
#pragma unroll
        for (int r = 0; r < 4; ++r) {
          int d = dt * 16 + quad * 4 + r;
          op[((size_t)bn * 128 + d) * 1024 + s] = oacc[h][dt][r];
        }
    }
  }
}

// ------------------------------------------------------------------
// 3x3 conv (r9 verified): BK=128 two-barrier + XCD chunked swizzle.
// ------------------------------------------------------------------
__global__ __launch_bounds__(256, 2) void k_conv(
    const __bf16* __restrict__ Wt, const __bf16* __restrict__ zp,
    float* __restrict__ part) {
  __shared__ __bf16 As[4 * 128 * 32];   // 32 KB
  __shared__ __bf16 Bs[4 * 128 * 32];   // 32 KB
  const int t = threadIdx.x;
  const int wave = t >> 6, lane = t & 63;
  const int l15 = lane & 15, quad = lane >> 4;

  const int Lb = blockIdx.x;            // 0..511
  const int logical = (Lb & 7) * 64 + (Lb >> 3);   // XCD-chunked (bijective)
  const int combo = logical & 7;
  const int ot = combo >> 1, sp = combo & 1;
  const int nt = logical >> 3;          // 8 contiguous nt per XCD = 1 batch
  const int mbase = ot * 128;
  const int nbase = nt * 128;
  const int cs = sp * 256;
  const int mh = (wave >> 1) * 64, nh = (wave & 1) * 64;

  const int row0 = t >> 2;
  const int part8 = (t & 3) * 8;
  const __bf16* gA0 = Wt + (size_t)(mbase + row0) * 512 + cs + part8;
  const __bf16* gA1 = gA0 + (size_t)64 * 512;
  const int n0 = nbase + row0;
  const int b0 = n0 >> 10, spn = n0 & 1023;
  const __bf16* gB0 =
      zp + ((size_t)(b0 * 34 + (spn >> 5) + 1) * 34 + (spn & 31) + 1) * 512 + cs + part8;
  const __bf16* gB1 = gB0 + (size_t)2 * 34 * 512;
  const int wofs = wave * 512;

  const f32x4 fz = {0.f, 0.f, 0.f, 0.f};
  f32x4 acc[4][4];
#pragma unroll
  for (int i = 0; i < 4; ++i)
#pragma unroll
    for (int j = 0; j < 4; ++j) acc[i][j] = fz;

#pragma unroll 1
  for (int tap = 0; tap < 9; ++tap) {
    const int dh = tap / 3 - 1, dw = tap % 3 - 1;
    const size_t aoff = (size_t)tap * 512 * 512;
    const int boff = (dh * 34 + dw) * 512;
#pragma unroll 1
    for (int k0 = 0; k0 < 256; k0 += 128) {
      __syncthreads();
#pragma unroll
      for (int c = 0; c < 4; ++c) {
        const int kq = k0 + c * 32;
        gld16(gA0 + aoff + kq, As + c * 4096 + wofs);
        gld16(gA1 + aoff + kq, As + c * 4096 + 2048 + wofs);
        gld16(gB0 + boff + kq, Bs + c * 4096 + wofs);
        gld16(gB1 + boff + kq, Bs + c * 4096 + 2048 + wofs);
      }
      __syncthreads();
#pragma unroll
      for (int c = 0; c < 4; ++c) {
        v8bf a[4], bfr[4];
#pragma unroll
        for (int i = 0; i < 4; ++i)
          a[i] = load8(&As[c * 4096 + (mh + i * 16 + l15) * 32 + quad * 8]);
#pragma unroll
        for (int j = 0; j < 4; ++j)
          bfr[j] = load8(&Bs[c * 4096 + (nh + j * 16 + l15) * 32 + quad * 8]);
#pragma unroll
        for (int i = 0; i < 4; ++i)
#pragma unroll
          for (int j = 0; j < 4; ++j) acc[i][j] = mfma16(a[i], bfr[j], acc[i][j]);
      }
    }
  }

  float* pout = part + (size_t)sp * 8 * 512 * 1024;
#pragma unroll
  for (int i = 0; i < 4; ++i)
#pragma unroll
    for (int j = 0; j < 4; ++j)
#pragma unroll
      for (int r = 0; r < 4; ++r) {
        int o = mbase + mh + i * 16 + quad * 4 + r;
        int nn = nbase + nh + j * 16 + l15;
        int bb2 = nn >> 10, s = nn & 1023;
        pout[((size_t)bb2 * 512 + o) * 1024 + s] = acc[i][j][r];
      }
}

// ------------------------------------------------------------------
// out = part0 + part1 + bias + x2   (f32x4 vectorized)
// ------------------------------------------------------------------
__global__ void k_sum(const float* __restrict__ part, const float* __restrict__ bias,
                      const float* __restrict__ x2, float* __restrict__ out) {
  int i = blockIdx.x * 256 + threadIdx.x;
  int o = (i >> 8) & 511;
  f32x4 p0 = reinterpret_cast<const f32x4*>(part)[i];
  f32x4 p1 = reinterpret_cast<const f32x4*>(part + (size_t)8 * 512 * 1024)[i];
  f32x4 xr = reinterpret_cast<const f32x4*>(x2)[i];
  float bo = bias[o];
  f32x4 r;
#pragma unroll
  for (int c = 0; c < 4; ++c) r[c] = p0[c] + p1[c] + bo + xr[c];
  reinterpret_cast<f32x4*>(out)[i] = r;
}

// ------------------------------------------------------------------
extern "C" void kernel_launch(void* const* d_in, const int* in_sizes, int n_in,
                              void* d_out, int out_size, void* d_ws, size_t ws_size,
                              hipStream_t stream) {
  const float* x    = (const float*)d_in[0];
  const float* wqk  = (const float*)d_in[1];
  const float* wv   = (const float*)d_in[2];
  const float* relh = (const float*)d_in[3];
  const float* relw = (const float*)d_in[4];
  const float* g1   = (const float*)d_in[5];
  const float* b1   = (const float*)d_in[6];
  const float* m1   = (const float*)d_in[7];
  const float* v1   = (const float*)d_in[8];
  const float* g2   = (const float*)d_in[9];
  const float* b2   = (const float*)d_in[10];
  const float* m2   = (const float*)d_in[11];
  const float* v2   = (const float*)d_in[12];
  const float* wfc  = (const float*)d_in[13];
  const float* bfc  = (const float*)d_in[14];
  float* out = (float*)d_out;

  char* p = (char*)d_ws;
  __bf16* y    = (__bf16*)p; p += (size_t)8 * 1024 * 512 * 2;       // (b,s,c)
  __bf16* qb   = (__bf16*)p; p += (size_t)8 * 4 * 1024 * 128 * 2;   // (b,n,s,d)
  __bf16* kb   = (__bf16*)p; p += (size_t)8 * 4 * 1024 * 128 * 2;   // (b,n,s,d)
  __bf16* vb   = (__bf16*)p; p += (size_t)8 * 4 * 1024 * 128 * 2;   // (b,n,d,s)
  __bf16* Wt   = (__bf16*)p; p += (size_t)9 * 512 * 512 * 2;        // (tap,o,c)
  __bf16* wqkb = (__bf16*)p; p += (size_t)1024 * 512 * 2;           // wall rows 0..1023
  __bf16* wvb  = (__bf16*)p; p += (size_t)512 * 512 * 2;            // wall rows 1024..1535
  __bf16* rhb  = (__bf16*)p; p += 32768;
  __bf16* rwb  = (__bf16*)p; p += 32768;
  float*  x2   = (float*)p;  p += (size_t)8 * 512 * 1024 * 4;       // o0 -> x2 (b,c,s) fp32
  __bf16* zpad = (__bf16*)p; p += (size_t)8 * 34 * 34 * 512 * 2;    // padded z
  // scratch aliases (live ranges disjoint):
  //   lpart: y region (y dead after k_proj; k_attn writes, k_bn2c reads,
  //          then k_conv's part overwrites)
  //   o1   : d_out (dead until k_sum writes it)
  //   part : d_ws base (y..vb dead after k_attn/k_bn2c)
  float* lpart = (float*)d_ws;
  float* o0 = x2;
  float* o1 = (float*)d_out;
  float* part = (float*)d_ws;

  k_prep<<<dim3(10568), dim3(256), 0, stream>>>(wqk, wv, relh, relw, wfc,
                                                wqkb, wvb, rhb, rwb, Wt,
                                                (float*)zpad, x, g1, b1, m1, v1, y);
  k_proj<<<dim3(768), dim3(256), 0, stream>>>(wqkb, y, qb, kb, vb);
  k_attn<<<dim3(512), dim3(256), 0, stream>>>(qb, kb, vb, rhb, rwb, o0, o1, lpart);
  k_bn2c<<<dim3(32, 16, 8), dim3(32, 8), 0, stream>>>(o0, o1, lpart, x,
                                                      g2, b2, m2, v2, zpad);
  k_conv<<<dim3(512), dim3(256), 0, stream>>>(Wt, zpad, part);
  k_sum<<<dim3(4096), dim3(256), 0, stream>>>(part, bfc, x2, out);
}

// Round 13
// 232.519 us; speedup vs baseline: 1.0900x; 1.0212x over previous
//
#include <hip/hip_runtime.h>

typedef __bf16 v8bf __attribute__((ext_vector_type(8)));
typedef float f32x4 __attribute__((ext_vector_type(4)));

#define DEVI static __device__ __forceinline__

DEVI v8bf load8(const __bf16* p) { return *reinterpret_cast<const v8bf*>(p); }

DEVI f32x4 mfma16(v8bf a, v8bf b, f32x4 c) {
  return __builtin_amdgcn_mfma_f32_16x16x32_bf16(a, b, c, 0, 0, 0);
}

// async global -> LDS, 16 bytes per lane. LDS dest: wave-uniform base + lane*16.
DEVI void gld16(const __bf16* g, __bf16* l) {
  __builtin_amdgcn_global_load_lds(
      (const __attribute__((address_space(1))) unsigned int*)(const void*)g,
      (__attribute__((address_space(3))) unsigned int*)(void*)l, 16, 0, 0);
}

#define SCALE_Q 0.08838834764831845f  // 128^-0.5

// ------------------------------------------------------------------
// Fused prologue: casts, conv-weight repack, zpad zero, BN1+ReLU
// transpose (absorbed k_bn1: blocks 6472..10567). One launch.
// ------------------------------------------------------------------
__global__ void k_prep(const float* __restrict__ wqk, const float* __restrict__ wv,
                       const float* __restrict__ relh, const float* __restrict__ relw,
                       const float* __restrict__ wfc, __bf16* __restrict__ wqkb,
                       __bf16* __restrict__ wvb, __bf16* __restrict__ rhb,
                       __bf16* __restrict__ rwb, __bf16* __restrict__ Wt,
                       float* __restrict__ zpad4, const float* __restrict__ x,
                       const float* __restrict__ g1, const float* __restrict__ b1,
                       const float* __restrict__ m1, const float* __restrict__ v1,
                       __bf16* __restrict__ y) {
  __shared__ float tile[32][33];
  const int bid = blockIdx.x, tid = threadIdx.x;
  if (bid >= 6472) {
    // ---- BN1 + ReLU + transpose (b,c,s) -> (b,s,c) bf16 ----
    const int local = bid - 6472;              // 0..4095
    const int b = local >> 9, c0 = ((local >> 5) & 15) * 32, s0 = (local & 31) * 32;
    const int tx = tid & 31, ty = tid >> 5;    // 32 x 8
#pragma unroll
    for (int r = 0; r < 4; ++r) {
      int c = c0 + ty + r * 8;
      float inv = g1[c] * rsqrtf(v1[c] + 1e-5f);
      float beta = b1[c] - m1[c] * inv;
      float val = x[((size_t)b * 512 + c) * 1024 + s0 + tx] * inv + beta;
      tile[ty + r * 8][tx] = fmaxf(val, 0.0f);
    }
    __syncthreads();
#pragma unroll
    for (int r = 0; r < 4; ++r) {
      int s = s0 + ty + r * 8;
      y[((size_t)b * 1024 + s) * 512 + c0 + tx] = (__bf16)tile[tx][ty + r * 8];
    }
    return;
  }
  if (bid < 2048) {
    int i = bid * 256 + tid;
    wqkb[i] = (__bf16)wqk[i];
  } else if (bid < 3072) {
    int i = (bid - 2048) * 256 + tid;
    wvb[i] = (__bf16)wv[i];
  } else if (bid < 3104) {
    int i = (bid - 3072) * 256 + tid;
    if (i < 8064) rhb[i] = (__bf16)relh[i];
  } else if (bid < 3136) {
    int i = (bid - 3104) * 256 + tid;
    if (i < 8064) rwb[i] = (__bf16)relw[i];
  } else if (bid < 4160) {
    int i = (bid - 3136) * 256 + tid;    // (o,c) pair
    const float* src = wfc + (size_t)i * 9;
#pragma unroll
    for (int tap = 0; tap < 9; ++tap)
      Wt[(size_t)tap * 262144 + i] = (__bf16)src[tap];
  } else {
    int i = (bid - 4160) * 256 + tid;
    f32x4 z = {0.f, 0.f, 0.f, 0.f};
    reinterpret_cast<f32x4*>(zpad4)[i] = z;
  }
}

// ------------------------------------------------------------------
// BN2 + split-K combine: x2 = (o0+o1)/(l0+l1) + x  (written in-place over
// o0, same flat index, per-thread read-before-write), then BN+ReLU ->
// padded (b,34,34,c) bf16. o1 lives in d_out (dead until k_sum).
// ------------------------------------------------------------------
__global__ void k_bn2c(float* o0x2, const float* __restrict__ o1,
                       const float* __restrict__ lp, const float* __restrict__ xin,
                       const float* __restrict__ g, const float* __restrict__ bb,
                       const float* __restrict__ m, const float* __restrict__ v,
                       __bf16* __restrict__ zp) {
  __shared__ float tile[32][33];
  const int b = blockIdx.z, c0 = blockIdx.y * 32, s0 = blockIdx.x * 32;
  const int tx = threadIdx.x, ty = threadIdx.y;
  const int bnrow = b * 4 + (c0 >> 7);     // c0..c0+31 stay in one 128-block
  const int scol = s0 + tx;
  const float linv =
      1.0f / (lp[bnrow * 1024 + scol] + lp[32768 + bnrow * 1024 + scol]);
#pragma unroll
  for (int r = 0; r < 4; ++r) {
    int c = c0 + ty + r * 8;
    float inv = g[c] * rsqrtf(v[c] + 1e-5f);
    float beta = bb[c] - m[c] * inv;
    size_t idx = ((size_t)b * 512 + c) * 1024 + scol;
    float t = (o0x2[idx] + o1[idx]) * linv + xin[idx];
    o0x2[idx] = t;                          // x2 for k_sum
    tile[ty + r * 8][tx] = fmaxf(t * inv + beta, 0.0f);
  }
  __syncthreads();
#pragma unroll
  for (int r = 0; r < 4; ++r) {
    int s = s0 + ty + r * 8;
    int hh = s >> 5, ww = s & 31;
    zp[(((size_t)b * 34 + hh + 1) * 34 + ww + 1) * 512 + c0 + tx] =
        (__bf16)tile[tx][ty + r * 8];
  }
}

// ------------------------------------------------------------------
// QKV projection, prefetch double-buffered + XCD-chunked swizzle
// (r12 verified).
// ------------------------------------------------------------------
__global__ __launch_bounds__(256) void k_proj(
    const __bf16* __restrict__ wall, const __bf16* __restrict__ y,
    __bf16* __restrict__ qout, __bf16* __restrict__ kout,
    __bf16* __restrict__ vout) {
  __shared__ __bf16 As[2][128 * 32];   // 16 KB
  __shared__ __bf16 Bs[2][128 * 32];   // 16 KB
  const int t = threadIdx.x;
  const int wave = t >> 6, lane = t & 63;
  const int l15 = lane & 15, quad = lane >> 4;
  const int Lb = blockIdx.x;            // 0..767
  const int logical = (Lb & 7) * 96 + (Lb >> 3);   // bijective
  const int nt = logical / 12, mt = logical % 12;
  const int mbase = mt * 128;           // o in [0,1536)
  const int nbase = nt * 128;           // flat (b,s)
  const int mh = (wave >> 1) * 64, nh = (wave & 1) * 64;
  const bool isv = mbase >= 1024;

  const int row0 = t >> 2, part8 = (t & 3) * 8;
  const __bf16* gA0 = wall + (size_t)(mbase + row0) * 512 + part8;
  const __bf16* gA1 = gA0 + (size_t)64 * 512;
  const __bf16* gB0 = y + (size_t)(nbase + row0) * 512 + part8;
  const __bf16* gB1 = gB0 + (size_t)64 * 512;
  const int wofs = wave * 512;

  const f32x4 fz = {0.f, 0.f, 0.f, 0.f};
  f32x4 acc[4][4];
#pragma unroll
  for (int i = 0; i < 4; ++i)
#pragma unroll
    for (int j = 0; j < 4; ++j) acc[i][j] = fz;

  // prologue: stage K-tile 0
  gld16(gA0, &As[0][wofs]);
  gld16(gA1, &As[0][2048 + wofs]);
  gld16(gB0, &Bs[0][wofs]);
  gld16(gB1, &Bs[0][2048 + wofs]);
  __syncthreads();

#pragma unroll 1
  for (int r = 0; r < 16; ++r) {
    const int cur = r & 1;
    if (r < 15) {
      const int kn = (r + 1) * 32;
      gld16(gA0 + kn, &As[cur ^ 1][wofs]);
      gld16(gA1 + kn, &As[cur ^ 1][2048 + wofs]);
      gld16(gB0 + kn, &Bs[cur ^ 1][wofs]);
      gld16(gB1 + kn, &Bs[cur ^ 1][2048 + wofs]);
    }
    v8bf a[4], bfr[4];
#pragma unroll
    for (int i = 0; i < 4; ++i)
      a[i] = load8(&As[cur][(mh + i * 16 + l15) * 32 + quad * 8]);
#pragma unroll
    for (int j = 0; j < 4; ++j)
      bfr[j] = load8(&Bs[cur][(nh + j * 16 + l15) * 32 + quad * 8]);
    if (isv) {
#pragma unroll
      for (int i = 0; i < 4; ++i)
#pragma unroll
        for (int j = 0; j < 4; ++j) acc[i][j] = mfma16(a[i], bfr[j], acc[i][j]);
    } else {
#pragma unroll
      for (int i = 0; i < 4; ++i)
#pragma unroll
        for (int j = 0; j < 4; ++j) acc[i][j] = mfma16(bfr[j], a[i], acc[i][j]);
    }
    __syncthreads();
  }

  if (isv) {
#pragma unroll
    for (int i = 0; i < 4; ++i)
#pragma unroll
      for (int j = 0; j < 4; ++j)
#pragma unroll
        for (int r = 0; r < 4; ++r) {
          int o = mbase + mh + i * 16 + quad * 4 + r;
          int nflat = nbase + nh + j * 16 + l15;
          int b = nflat >> 10, s = nflat & 1023;
          int oe = o - 1024; int n = oe >> 7, d = oe & 127;
          vout[(((size_t)b * 4 + n) * 128 + d) * 1024 + s] = (__bf16)acc[i][j][r];
        }
  } else {
    const bool isq = mbase < 512;
#pragma unroll
    for (int i = 0; i < 4; ++i)
#pragma unroll
      for (int j = 0; j < 4; ++j)
#pragma unroll
        for (int r = 0; r < 4; ++r) {
          int o = mbase + mh + i * 16 + l15;
          int nflat = nbase + nh + j * 16 + quad * 4 + r;
          int b = nflat >> 10, s = nflat & 1023;
          float val = acc[i][j][r];
          if (isq) {
            int n = o >> 7, d = o & 127;
            qout[(((size_t)b * 4 + n) * 1024 + s) * 128 + d] = (__bf16)(val * SCALE_Q);
          } else {
            int oe = o - 512; int n = oe >> 7, d = oe & 127;
            kout[(((size_t)b * 4 + n) * 1024 + s) * 128 + d] = (__bf16)val;
          }
        }
  }
}

// ------------------------------------------------------------------
// Flash attention v15 = v14 with KVBLK=64: 8 iters x 2 barriers = 16
// drains (was 32). Mechanism = barrier amortization (the r8->r9 conv
// lesson: BK=128's 18 pairs beat BK=64's 36 at identical traffic).
// Staging = two of v14's verified 32-row sub-stages per group (same
// per-call mapping + jh index). Ledger: per iter issue 4 K then 4 V
// calls; top vmcnt(4) drains K (oldest 4 of 8), mid vmcnt(0) drains V.
// Ks overwrite + Vs-dbuf WAR arguments identical to v14 (passed r11/12).
// LDS 80384 B -> still 2 blocks/CU. RHs trimmed to the 16 used cols
// (rel-indexed, nt==half only).
// ------------------------------------------------------------------
__global__ __launch_bounds__(256, 2) void k_attn(
    const __bf16* __restrict__ q, const __bf16* __restrict__ kmat,
    const __bf16* __restrict__ vt, const __bf16* __restrict__ relh,
    const __bf16* __restrict__ relw, float* __restrict__ o0,
    float* __restrict__ o1, float* __restrict__ lpart) {
  __shared__ __bf16 Ks[2 * 4096];        // 16 KB: [jh][kk][32 j][32 d]
  __shared__ __bf16 Vs[2][2 * 4096];     // 32 KB: [buf][jh][128 d][32 j]
  __shared__ __bf16 P[4 * 32 * 72];      // 18 KB, wave-private bands
  __shared__ __bf16 RWs[128][33];        // 8.4 KB, wave-private bands
  __shared__ __bf16 RHs[128][17];        // 4.25 KB, rel cols 0..16
  // total 80384 B <= 81920 (2 blocks/CU)

  const int Lb = blockIdx.x;             // 0..511
  const int xcd = Lb & 7, local = Lb >> 3;   // local 0..63
  const int bn = xcd * 4 + (local & 3);
  const int qblk = (local >> 2) & 7;     // 0..7 : 128 q-rows each
  const int half = local >> 5;           // 0..1 : key-range split
  const int s0 = qblk * 128;

  const int t = threadIdx.x;
  const int wave = t >> 6, lane = t & 63;
  const int l15 = lane & 15, quad = lane >> 4;
  const size_t hoff = ((size_t)bn) << 17;
  const int s0w = s0 + wave * 32;        // wave owns rows s0w..s0w+31
  const int h0w = s0w >> 5;              // = qblk*4 + wave (32-aligned span)
  const int j00 = half * 512;

  // staging source pointers (identical per-call mapping to v14)
  const __bf16* kgA =
      kmat + hoff + (size_t)((t >> 2) & 31) * 128 + (t >> 7) * 32 + (t & 3) * 8;
  const __bf16* vgA = vt + hoff + (size_t)(t >> 2) * 1024 + (t & 3) * 8;
  const int wofs = wave * 512;

  // issue first K tile (4 calls) then V tile (4 calls)
#pragma unroll
  for (int jh = 0; jh < 2; ++jh)
#pragma unroll
    for (int c = 0; c < 2; ++c)
      gld16(kgA + (size_t)(j00 + jh * 32) * 128 + c * 64,
            Ks + jh * 4096 + wofs + c * 2048);
#pragma unroll
  for (int jh = 0; jh < 2; ++jh)
#pragma unroll
    for (int dh = 0; dh < 2; ++dh)
      gld16(vgA + (size_t)dh * 64 * 1024 + j00 + jh * 32,
            Vs[0] + jh * 4096 + wofs + dh * 2048);

  v8bf aq[2][4];
#pragma unroll
  for (int h = 0; h < 2; ++h) {
    const __bf16* qp = q + hoff + (size_t)(s0w + h * 16 + l15) * 128;
#pragma unroll
    for (int kk = 0; kk < 4; ++kk) aq[h][kk] = load8(qp + kk * 32 + quad * 8);
  }

  const f32x4 fz = {0.f, 0.f, 0.f, 0.f};
#pragma unroll
  for (int h = 0; h < 2; ++h) {
#pragma unroll
    for (int nt = 0; nt < 4; ++nt) {     // RWs via shift-write
      int rr = nt * 16 + l15;
      const __bf16* bp = relw + (size_t)rr * 128;
      f32x4 acc = fz;
#pragma unroll
      for (int kk = 0; kk < 4; ++kk)
        acc = mfma16(aq[h][kk], load8(bp + kk * 32 + quad * 8), acc);
#pragma unroll
      for (int r = 0; r < 4; ++r) {
        int row15 = quad * 4 + r;
        int wj = rr + h * 16 + row15 - 31;     // ww = h*16+row15 (s0w 32-aligned)
        if (wj >= 0 && wj < 32)
          RWs[wave * 32 + h * 16 + row15][wj] = (__bf16)acc[r];
      }
    }
    {  // RHs: single 16-col block for this key half, rel-indexed
      int hj = half * 16 + l15;          // absolute h-block of key range
      const __bf16* bp = relh + (size_t)(hj - h0w + 31) * 128;
      f32x4 acc = fz;
#pragma unroll
      for (int kk = 0; kk < 4; ++kk)
        acc = mfma16(aq[h][kk], load8(bp + kk * 32 + quad * 8), acc);
#pragma unroll
      for (int r = 0; r < 4; ++r)
        RHs[wave * 32 + h * 16 + quad * 4 + r][l15] = (__bf16)acc[r];
    }
  }

  // rel-W bias is periodic in j (mod 32): hoist per-row values
  // (wave-private band, same wave wrote it -> in-order LDS, no barrier).
  float rwreg[2][4][2];
#pragma unroll
  for (int h = 0; h < 2; ++h)
#pragma unroll
    for (int r = 0; r < 4; ++r) {
      const int gi = wave * 32 + h * 16 + quad * 4 + r;
      rwreg[h][r][0] = (float)RWs[gi][l15];
      rwreg[h][r][1] = (float)RWs[gi][l15 + 16];
    }

  __syncthreads();   // bias tables visible; first K/V tile landed (vmcnt 0)

  float lsum[2][4];
#pragma unroll
  for (int h = 0; h < 2; ++h)
#pragma unroll
    for (int r = 0; r < 4; ++r) lsum[h][r] = 0.f;
  f32x4 oacc[2][8];
#pragma unroll
  for (int h = 0; h < 2; ++h)
#pragma unroll
    for (int dt = 0; dt < 8; ++dt) oacc[h][dt] = fz;
  __bf16* Pw = P + wave * 32 * 72;

#pragma unroll 1
  for (int iter = 0; iter < 8; ++iter) {
    // top: K_t ready-gate (outstanding: K_t oldest 4, V_t newest 4).
    asm volatile("s_waitcnt vmcnt(4)" ::: "memory");
    __builtin_amdgcn_s_barrier();
    __builtin_amdgcn_sched_barrier(0);

    // QK^T (32 MFMA covering 32q x 64j); kf loaded in two 8-reg halves
    f32x4 sacc[2][4];
    __builtin_amdgcn_s_setprio(1);
#pragma unroll
    for (int njh = 0; njh < 2; ++njh) {
      v8bf kf[8];
#pragma unroll
      for (int nj1 = 0; nj1 < 2; ++nj1)
#pragma unroll
        for (int kk = 0; kk < 4; ++kk)
          kf[nj1 * 4 + kk] = load8(
              &Ks[njh * 4096 + kk * 1024 + (nj1 * 16 + l15) * 32 + quad * 8]);
#pragma unroll
      for (int h = 0; h < 2; ++h)
#pragma unroll
        for (int nj1 = 0; nj1 < 2; ++nj1) {
          f32x4 a = fz;
#pragma unroll
          for (int kk = 0; kk < 4; ++kk)
            a = mfma16(aq[h][kk], kf[nj1 * 4 + kk], a);
          sacc[h][njh * 2 + nj1] = a;
        }
    }
    __builtin_amdgcn_s_setprio(0);

    // bias + exp(c=0) + partial l + stash P (wave-private band)
    const int hjr = iter * 2;            // rel col in RHs
#pragma unroll
    for (int h = 0; h < 2; ++h)
#pragma unroll
      for (int r = 0; r < 4; ++r) {
        const int row = h * 16 + quad * 4 + r;      // wave-local row
        const float rh0 = (float)RHs[wave * 32 + row][hjr];
        const float rh1 = (float)RHs[wave * 32 + row][hjr + 1];
#pragma unroll
        for (int nj = 0; nj < 4; ++nj) {
          float val = sacc[h][nj][r] + rwreg[h][r][nj & 1] + ((nj & 2) ? rh1 : rh0);
          float p = __expf(fminf(val, 60.0f));
          lsum[h][r] += p;
          Pw[row * 72 + (nj >> 1) * 36 + (nj & 1) * 16 + l15] = (__bf16)p;
        }
      }
    v8bf pf[2][2];
#pragma unroll
    for (int h = 0; h < 2; ++h)
#pragma unroll
      for (int kk2 = 0; kk2 < 2; ++kk2)
        pf[h][kk2] = *reinterpret_cast<const v8bf*>(
            &Pw[(h * 16 + l15) * 72 + kk2 * 36 + quad * 8]);

    // mid: V_t ready-gate; all waves past QK^T -> Ks overwrite safe.
    asm volatile("s_waitcnt vmcnt(0)" ::: "memory");
    __builtin_amdgcn_s_barrier();
    __builtin_amdgcn_sched_barrier(0);

    // issue K[t+1] (covered by PV phase below)
    if (iter < 7) {
      const int jn = j00 + (iter + 1) * 64;
#pragma unroll
      for (int jh = 0; jh < 2; ++jh)
#pragma unroll
        for (int c = 0; c < 2; ++c)
          gld16(kgA + (size_t)(jn + jh * 32) * 128 + c * 64,
                Ks + jh * 4096 + wofs + c * 2048);
    }

    // PV as O^T = V * P^T (32 MFMA): V-frag read once, used by both h.
    const __bf16* vcur = Vs[iter & 1];
    __builtin_amdgcn_s_setprio(1);
#pragma unroll
    for (int dt = 0; dt < 8; ++dt) {
      f32x4 a0 = oacc[0][dt], a1 = oacc[1][dt];
#pragma unroll
      for (int kk2 = 0; kk2 < 2; ++kk2) {
        v8bf vf = load8(&vcur[kk2 * 4096 + (dt * 16 + l15) * 32 + quad * 8]);
        a0 = mfma16(vf, pf[0][kk2], a0);
        a1 = mfma16(vf, pf[1][kk2], a1);
      }
      oacc[0][dt] = a0;
      oacc[1][dt] = a1;
    }
    __builtin_amdgcn_s_setprio(0);

    // V[t+1] -> other buffer: WAR carried by next iteration's top-barrier
    // chain (readers of that buffer finished a full iteration ago).
    if (iter < 7) {
      __builtin_amdgcn_sched_barrier(0);
      const int jn = j00 + (iter + 1) * 64;
      __bf16* vnext = Vs[(iter + 1) & 1];
#pragma unroll
      for (int jh = 0; jh < 2; ++jh)
#pragma unroll
        for (int dh = 0; dh < 2; ++dh)
          gld16(vgA + (size_t)dh * 64 * 1024 + jn + jh * 32,
                vnext + jh * 4096 + wofs + dh * 2048);
    }
  }

  // partial l: reduce across the 16-lane groups, store per-row by l15==0
#pragma unroll
  for (int h = 0; h < 2; ++h)
#pragma unroll
    for (int r = 0; r < 4; ++r) {
#pragma unroll
      for (int msk = 8; msk >= 1; msk >>= 1)
        lsum[h][r] += __shfl_xor(lsum[h][r], msk);
    }
  if (l15 == 0) {
#pragma unroll
    for (int h = 0; h < 2; ++h)
#pragma unroll
      for (int r = 0; r < 4; ++r)
        lpart[half * 32768 + bn * 1024 + s0w + h * 16 + quad * 4 + r] =
            lsum[h][r];
  }

  // partial O store (unnormalized): lane = query s -> coalesced
  {
    float* op = half ? o1 : o0;
#pragma unroll
    for (int h = 0; h < 2; ++h) {
      const int s = s0w + h * 16 + l15;
#pragma unroll
      for (int dt = 0; dt < 8; ++dt)
#pragma unroll
        for (int r = 0; r < 4; ++r) {
          int d = dt * 16 + quad * 4 + r;
          op[((size_t)bn * 128 + d) * 1024 + s] = oacc[h][dt][r];
        }
    }
  }
}

// ------------------------------------------------------------------
// 3x3 conv (r9 verified): BK=128 two-barrier + XCD chunked swizzle.
// ------------------------------------------------------------------
__global__ __launch_bounds__(256, 2) void k_conv(
    const __bf16* __restrict__ Wt, const __bf16* __restrict__ zp,
    float* __restrict__ part) {
  __shared__ __bf16 As[4 * 128 * 32];   // 32 KB
  __shared__ __bf16 Bs[4 * 128 * 32];   // 32 KB
  const int t = threadIdx.x;
  const int wave = t >> 6, lane = t & 63;
  const int l15 = lane & 15, quad = lane >> 4;

  const int Lb = blockIdx.x;            // 0..511
  const int logical = (Lb & 7) * 64 + (Lb >> 3);   // XCD-chunked (bijective)
  const int combo = logical & 7;
  const int ot = combo >> 1, sp = combo & 1;
  const int nt = logical >> 3;          // 8 contiguous nt per XCD = 1 batch
  const int mbase = ot * 128;
  const int nbase = nt * 128;
  const int cs = sp * 256;
  const int mh = (wave >> 1) * 64, nh = (wave & 1) * 64;

  const int row0 = t >> 2;
  const int part8 = (t & 3) * 8;
  const __bf16* gA0 = Wt + (size_t)(mbase + row0) * 512 + cs + part8;
  const __bf16* gA1 = gA0 + (size_t)64 * 512;
  const int n0 = nbase + row0;
  const int b0 = n0 >> 10, spn = n0 & 1023;
  const __bf16* gB0 =
      zp + ((size_t)(b0 * 34 + (spn >> 5) + 1) * 34 + (spn & 31) + 1) * 512 + cs + part8;
  const __bf16* gB1 = gB0 + (size_t)2 * 34 * 512;
  const int wofs = wave * 512;

  const f32x4 fz = {0.f, 0.f, 0.f, 0.f};
  f32x4 acc[4][4];
#pragma unroll
  for (int i = 0; i < 4; ++i)
#pragma unroll
    for (int j = 0; j < 4; ++j) acc[i][j] = fz;

#pragma unroll 1
  for (int tap = 0; tap < 9; ++tap) {
    const int dh = tap / 3 - 1, dw = tap % 3 - 1;
    const size_t aoff = (size_t)tap * 512 * 512;
    const int boff = (dh * 34 + dw) * 512;
#pragma unroll 1
    for (int k0 = 0; k0 < 256; k0 += 128) {
      __syncthreads();
#pragma unroll
      for (int c = 0; c < 4; ++c) {
        const int kq = k0 + c * 32;
        gld16(gA0 + aoff + kq, As + c * 4096 + wofs);
        gld16(gA1 + aoff + kq, As + c * 4096 + 2048 + wofs);
        gld16(gB0 + boff + kq, Bs + c * 4096 + wofs);
        gld16(gB1 + boff + kq, Bs + c * 4096 + 2048 + wofs);
      }
      __syncthreads();
#pragma unroll
      for (int c = 0; c < 4; ++c) {
        v8bf a[4], bfr[4];
#pragma unroll
        for (int i = 0; i < 4; ++i)
          a[i] = load8(&As[c * 4096 + (mh + i * 16 + l15) * 32 + quad * 8]);
#pragma unroll
        for (int j = 0; j < 4; ++j)
          bfr[j] = load8(&Bs[c * 4096 + (nh + j * 16 + l15) * 32 + quad * 8]);
#pragma unroll
        for (int i = 0; i < 4; ++i)
#pragma unroll
          for (int j = 0; j < 4; ++j) acc[i][j] = mfma16(a[i], bfr[j], acc[i][j]);
      }
    }
  }

  float* pout = part + (size_t)sp * 8 * 512 * 1024;
#pragma unroll
  for (int i = 0; i < 4; ++i)
#pragma unroll
    for (int j = 0; j < 4; ++j)
#pragma unroll
      for (int r = 0; r < 4; ++r) {
        int o = mbase + mh + i * 16 + quad * 4 + r;
        int nn = nbase + nh + j * 16 + l15;
        int bb2 = nn >> 10, s = nn & 1023;
        pout[((size_t)bb2 * 512 + o) * 1024 + s] = acc[i][j][r];
      }
}

// ------------------------------------------------------------------
// out = part0 + part1 + bias + x2   (f32x4 vectorized)
// ------------------------------------------------------------------
__global__ void k_sum(const float* __restrict__ part, const float* __restrict__ bias,
                      const float* __restrict__ x2, float* __restrict__ out) {
  int i = blockIdx.x * 256 + threadIdx.x;
  int o = (i >> 8) & 511;
  f32x4 p0 = reinterpret_cast<const f32x4*>(part)[i];
  f32x4 p1 = reinterpret_cast<const f32x4*>(part + (size_t)8 * 512 * 1024)[i];
  f32x4 xr = reinterpret_cast<const f32x4*>(x2)[i];
  float bo = bias[o];
  f32x4 r;
#pragma unroll
  for (int c = 0; c < 4; ++c) r[c] = p0[c] + p1[c] + bo + xr[c];
  reinterpret_cast<f32x4*>(out)[i] = r;
}

// ------------------------------------------------------------------
extern "C" void kernel_launch(void* const* d_in, const int* in_sizes, int n_in,
                              void* d_out, int out_size, void* d_ws, size_t ws_size,
                              hipStream_t stream) {
  const float* x    = (const float*)d_in[0];
  const float* wqk  = (const float*)d_in[1];
  const float* wv   = (const float*)d_in[2];
  const float* relh = (const float*)d_in[3];
  const float* relw = (const float*)d_in[4];
  const float* g1   = (const float*)d_in[5];
  const float* b1   = (const float*)d_in[6];
  const float* m1   = (const float*)d_in[7];
  const float* v1   = (const float*)d_in[8];
  const float* g2   = (const float*)d_in[9];
  const float* b2   = (const float*)d_in[10];
  const float* m2   = (const float*)d_in[11];
  const float* v2   = (const float*)d_in[12];
  const float* wfc  = (const float*)d_in[13];
  const float* bfc  = (const float*)d_in[14];
  float* out = (float*)d_out;

  char* p = (char*)d_ws;
  __bf16* y    = (__bf16*)p; p += (size_t)8 * 1024 * 512 * 2;       // (b,s,c)
  __bf16* qb   = (__bf16*)p; p += (size_t)8 * 4 * 1024 * 128 * 2;   // (b,n,s,d)
  __bf16* kb   = (__bf16*)p; p += (size_t)8 * 4 * 1024 * 128 * 2;   // (b,n,s,d)
  __bf16* vb   = (__bf16*)p; p += (size_t)8 * 4 * 1024 * 128 * 2;   // (b,n,d,s)
  __bf16* Wt   = (__bf16*)p; p += (size_t)9 * 512 * 512 * 2;        // (tap,o,c)
  __bf16* wqkb = (__bf16*)p; p += (size_t)1024 * 512 * 2;           // wall rows 0..1023
  __bf16* wvb  = (__bf16*)p; p += (size_t)512 * 512 * 2;            // wall rows 1024..1535
  __bf16* rhb  = (__bf16*)p; p += 32768;
  __bf16* rwb  = (__bf16*)p; p += 32768;
  float*  x2   = (float*)p;  p += (size_t)8 * 512 * 1024 * 4;       // o0 -> x2 (b,c,s) fp32
  __bf16* zpad = (__bf16*)p; p += (size_t)8 * 34 * 34 * 512 * 2;    // padded z
  // scratch aliases (live ranges disjoint):
  //   lpart: y region (y dead after k_proj; k_attn writes, k_bn2c reads,
  //          then k_conv's part overwrites)
  //   o1   : d_out (dead until k_sum writes it)
  //   part : d_ws base (y..vb dead after k_attn/k_bn2c)
  float* lpart = (float*)d_ws;
  float* o0 = x2;
  float* o1 = (float*)d_out;
  float* part = (float*)d_ws;

  k_prep<<<dim3(10568), dim3(256), 0, stream>>>(wqk, wv, relh, relw, wfc,
                                                wqkb, wvb, rhb, rwb, Wt,
                                                (float*)zpad, x, g1, b1, m1, v1, y);
  k_proj<<<dim3(768), dim3(256), 0, stream>>>(wqkb, y, qb, kb, vb);
  k_attn<<<dim3(512), dim3(256), 0, stream>>>(qb, kb, vb, rhb, rwb, o0, o1, lpart);
  k_bn2c<<<dim3(32, 16, 8), dim3(32, 8), 0, stream>>>(o0, o1, lpart, x,
                                                      g2, b2, m2, v2, zpad);
  k_conv<<<dim3(512), dim3(256), 0, stream>>>(Wt, zpad, part);
  k_sum<<<dim3(4096), dim3(256), 0, stream>>>(part, bfc, x2, out);
}